// Round 5
// baseline (944.081 us; speedup 1.0000x reference)
//
#include <hip/hip_runtime.h>
#include <math.h>

// B,S,D,K,DF,H,DFF = 2,512,512,8,64,8,2048
#define BB 2
#define SS 512
#define DD 512
#define HH 8
#define DFF 2048

typedef __attribute__((ext_vector_type(8))) short bf16x8;
typedef __attribute__((ext_vector_type(4))) float f32x4;

__device__ __forceinline__ float gelu_exact(float v) {
    return 0.5f * v * (1.0f + erff(v * 0.70710678118654752f));
}
__device__ __forceinline__ unsigned short f2bf(float f) {
    unsigned u = __float_as_uint(f);
    u += 0x7FFF + ((u >> 16) & 1);
    return (unsigned short)(u >> 16);
}
__device__ __forceinline__ float bf2f(unsigned short s) {
    return __uint_as_float(((unsigned)s) << 16);
}
__device__ __forceinline__ void gload16(const void* g, void* l) {
    __builtin_amdgcn_global_load_lds((const __attribute__((address_space(1))) void*)g,
                                     (__attribute__((address_space(3))) void*)l, 16, 0, 0);
}

// ---------------- flexible bf16 MFMA GEMM: C = epi(A @ B^T) ----------------
// A [M,K] bf16 (lda), B [N,K] bf16 (ldb, i.e. B^T layout). 128xNT tile, BK=32,
// 256 threads (4 waves 2x2), 16x16x32 MFMA. Batched over blockIdx.z.
// EPI: 0 fp32 out (scale, no bias) | 1 fp32 bias+gelu | 2 bf16 perm-bias (fc2)
//      3 bf16 out (+opt bias)      | 4 fp32 bias+resid | 5 bf16 vT-store
//      6 bf16 upT2-store
template<int NT, int EPI>
__global__ __launch_bounds__(256)
void mgemm_k(const unsigned short* __restrict__ A, const unsigned short* __restrict__ B,
             const float* __restrict__ bias, const float* __restrict__ resid,
             float* __restrict__ Cf, unsigned short* __restrict__ Cb,
             int K, int lda, int ldb, int ldc, int batchH,
             long aSB, long aSH, long bSB, long bSH, long cSB, long cSH,
             float scale)
{
    __shared__ unsigned short As[128][32];
    __shared__ unsigned short Bs[NT][32];
    const int tid = threadIdx.x;
    const int wave = tid >> 6, lane = tid & 63;
    const int z = blockIdx.z;
    const int zb = z / batchH, zh = z % batchH;
    const unsigned short* Ab = A + (long)zb * aSB + (long)zh * aSH;
    const unsigned short* Bb = B + (long)zb * bSB + (long)zh * bSH;
    const int row0 = blockIdx.y * 128, col0 = blockIdx.x * NT;
    const int wm = wave >> 1, wn = wave & 1;
    const int lm = lane & 15, quad = lane >> 4;
    const int lrow = lane >> 2, lk = (lane & 3) * 8;
    constexpr int NTW = NT / 32;     // n-subtiles per wave
    f32x4 acc[4][NTW];
    #pragma unroll
    for (int i = 0; i < 4; ++i)
        #pragma unroll
        for (int j = 0; j < NTW; ++j) acc[i][j] = (f32x4)0.f;

    for (int k0 = 0; k0 < K; k0 += 32) {
        #pragma unroll
        for (int t = 0; t < 2; ++t) {
            const int r = wave * 32 + t * 16;
            gload16(Ab + (long)(row0 + r + lrow) * lda + k0 + lk, &As[r][0]);
        }
        if (NT == 128) {
            #pragma unroll
            for (int t = 0; t < 2; ++t) {
                const int r = wave * 32 + t * 16;
                gload16(Bb + (long)(col0 + r + lrow) * ldb + k0 + lk, &Bs[r][0]);
            }
        } else {
            const int r = wave * 16;
            gload16(Bb + (long)(col0 + r + lrow) * ldb + k0 + lk, &Bs[r][0]);
        }
        __syncthreads();
        bf16x8 af[4], bfr[NTW];
        #pragma unroll
        for (int mt = 0; mt < 4; ++mt)
            af[mt] = *(const bf16x8*)&As[wm * 64 + mt * 16 + lm][quad * 8];
        #pragma unroll
        for (int nt = 0; nt < NTW; ++nt)
            bfr[nt] = *(const bf16x8*)&Bs[wn * (NT / 2) + nt * 16 + lm][quad * 8];
        #pragma unroll
        for (int mt = 0; mt < 4; ++mt)
            #pragma unroll
            for (int nt = 0; nt < NTW; ++nt)
                acc[mt][nt] = __builtin_amdgcn_mfma_f32_16x16x32_bf16(
                    af[mt], bfr[nt], acc[mt][nt], 0, 0, 0);
        __syncthreads();
    }
    float* Cfz = Cf ? Cf + (long)zb * cSB + (long)zh * cSH : nullptr;
    unsigned short* Cbz = Cb ? Cb + (long)zb * cSB + (long)zh * cSH : nullptr;
    #pragma unroll
    for (int mt = 0; mt < 4; ++mt) {
        #pragma unroll
        for (int nt = 0; nt < NTW; ++nt) {
            #pragma unroll
            for (int r = 0; r < 4; ++r) {
                const int row = row0 + wm * 64 + mt * 16 + quad * 4 + r;
                const int col = col0 + wn * (NT / 2) + nt * 16 + lm;
                float v = acc[mt][nt][r] * scale;
                if (EPI == 2)      v += bias[(col & 511) * 64 + (col >> 9)];
                else if (EPI == 1 || EPI == 4) v += bias[col];
                else if ((EPI == 3 || EPI == 5 || EPI == 6) && bias) v += bias[col];
                if (EPI == 1) v = gelu_exact(v);
                if (EPI == 4) v += resid[(long)row * ldc + col];
                if (EPI == 0 || EPI == 1 || EPI == 4)
                    Cfz[(long)row * ldc + col] = v;
                else if (EPI == 2 || EPI == 3)
                    Cbz[(long)row * ldc + col] = f2bf(v);
                else if (EPI == 5)  // vT[b][h][c][j]: rows=(b,j), col=h*64+c
                    Cb[(long)(row >> 9) * 262144 + (col >> 6) * 32768 +
                       (col & 63) * 512 + (row & 511)] = f2bf(v);
                else if (EPI == 6)  // upT2[b][c][j*8+l]: rows=(b,j), col=l*64+c
                    Cb[(long)(row >> 9) * 262144 + (col & 63) * 4096 +
                       (row & 511) * 8 + (col >> 6)] = f2bf(v);
            }
        }
    }
}

// ---------- fc2: 256x256-tile 8-wave 4-phase pipelined GEMM (T2+T3+T4+T5) ----------
// C[1024][32768] = bf16( A[1024][2048] @ B^T (B=[32768][2048]) + perm-bias ).
// 512 threads = 8 waves (2m x 4n), per-wave 128x64 out, BK=64, LDS 160 KiB:
//   A double-buffered  (2 bufs x 2 halves x [128][64] bf16 = 64 KiB)  - L2-resident
//   B TRIPLE-buffered  (3 bufs x 2 halves x [128][64] bf16 = 96 KiB)  - HBM stream,
//     staged 2 tiles (5-6 phases ~ 600-1000cy) ahead to cover HBM latency.
// A-half h: global row = row0 + h*64 + (r<64 ? r : 64+r)   (64-row granules {h,h+2})
// B-half h: global row = col0 + (r>>5)*64 + h*32 + (r&31)  (interleaved 32-granules)
// Per tile t: issue {A0_{t+1}@ph0, A1_{t+1}@ph1, B0_{t+2}@ph2, B1_{t+2}@ph3};
// counted drains ONLY at ph1 vmcnt(8) (lands A1_t) and ph3 vmcnt(6) (lands
// B0_{t+1},B1_{t+1},A0_{t+1}). Steady invariant entering ph0(t):
// outstanding = {A1_t, B0_{t+1}, B1_{t+1}} (6 loads). Uniform 32-iter loop;
// tail stages clamp to tile 31 (redundant loads into never-read bufs keep
// vmcnt counts uniform). LDS swizzle: 16B-chunk ^= (row&7), pre-swizzled
// global source + swizzled ds_read (rule #21).
__global__ __launch_bounds__(512, 2)
void fc2_k(const unsigned short* __restrict__ A, const unsigned short* __restrict__ Bm,
           const float* __restrict__ bias, unsigned short* __restrict__ C)
{
    extern __shared__ unsigned short smraw[];   // 81920 shorts = 160 KiB
#define SMA(ab, h) (smraw + (((ab) * 2 + (h)) * 8192))
#define SMB(bb, h) (smraw + (32768 + ((bb) * 2 + (h)) * 8192))
    const int tid = threadIdx.x;
    const int wave = tid >> 6, lane = tid & 63;
    // bijective XCD swizzle (512 blocks, 512%8==0); bx-major so the 4
    // row-blocks sharing a B panel are adjacent on one XCD.
    const int bid = blockIdx.x;
    const int lin = (bid & 7) * 64 + (bid >> 3);
    const int by = lin & 3, bx = lin >> 2;
    const int row0 = by * 256, col0 = bx * 256;
    const int wm = wave >> 2, wn = wave & 3;          // 2 x 4 wave grid
    const int lm = lane & 15, quad = lane >> 4;
    // frag-read addressing (element offsets inside one [128][64] half)
    const int axor = lm & 7;
    const int arow = (wm * 64 + lm) * 64;
    const int brow = (wn * 32 + lm) * 64;
    const int ca0 = ((quad) ^ axor) * 8;              // kk=0 chunk
    const int ca1 = ((quad + 4) ^ axor) * 8;          // kk=1 chunk
    // stage addressing: lane covers 16B chunk (lane&7) of local row wave*8+(lane>>3)
    const int srow = wave * 8 + (lane >> 3);          // local row r in [0,64)
    const int scx = ((lane & 7) ^ ((lane >> 3) & 7)) * 8;  // pre-swizzled source chunk
    const int sbrow = ((srow >> 5) << 6) + (srow & 31);    // B granule-interleave row
    const unsigned short* AgB = A + (long)(row0 + srow) * 2048 + scx;
    const unsigned short* BgB = Bm + (long)(col0 + sbrow) * 2048 + scx;

    f32x4 acc[8][4];
    #pragma unroll
    for (int i = 0; i < 8; ++i)
        #pragma unroll
        for (int j = 0; j < 4; ++j) acc[i][j] = (f32x4)0.f;
    bf16x8 afr[4][2], b0f[2][2], b1f[2][2];

#define STGA(ab, h, toff) do { \
        const unsigned short* _g = AgB + (toff) * 64 + (h) * (64 * 2048); \
        unsigned short* _d = SMA(ab, h) + wave * 512; \
        gload16(_g, _d); \
        gload16(_g + 128 * 2048, _d + 4096); \
    } while (0)
#define STGB(bb, h, toff) do { \
        const unsigned short* _g = BgB + (toff) * 64 + (h) * (32 * 2048); \
        unsigned short* _d = SMB(bb, h) + wave * 512; \
        gload16(_g, _d); \
        gload16(_g + 128 * 2048, _d + 4096); \
    } while (0)
#define RDA(Hp) do { _Pragma("unroll") for (int _m = 0; _m < 4; ++_m) { \
        afr[_m][0] = *(const bf16x8*)((Hp) + arow + _m * 1024 + ca0); \
        afr[_m][1] = *(const bf16x8*)((Hp) + arow + _m * 1024 + ca1); } } while (0)
#define RDB(bf, Hp) do { _Pragma("unroll") for (int _n = 0; _n < 2; ++_n) { \
        bf[_n][0] = *(const bf16x8*)((Hp) + brow + _n * 1024 + ca0); \
        bf[_n][1] = *(const bf16x8*)((Hp) + brow + _n * 1024 + ca1); } } while (0)
#define MM(QM, QN, bf) do { _Pragma("unroll") for (int _m = 0; _m < 4; ++_m) \
        _Pragma("unroll") for (int _n = 0; _n < 2; ++_n) { \
        acc[(QM)*4+_m][(QN)*2+_n] = __builtin_amdgcn_mfma_f32_16x16x32_bf16( \
            afr[_m][0], bf[_n][0], acc[(QM)*4+_m][(QN)*2+_n], 0, 0, 0); \
        acc[(QM)*4+_m][(QN)*2+_n] = __builtin_amdgcn_mfma_f32_16x16x32_bf16( \
            afr[_m][1], bf[_n][1], acc[(QM)*4+_m][(QN)*2+_n], 0, 0, 0); } } while (0)
#define PH_MID() \
        __builtin_amdgcn_s_barrier(); \
        asm volatile("s_waitcnt lgkmcnt(0)" ::: "memory"); \
        __builtin_amdgcn_sched_barrier(0); \
        __builtin_amdgcn_s_setprio(1)
#define PH_END(VM) \
        __builtin_amdgcn_s_setprio(0); \
        __builtin_amdgcn_sched_barrier(0); \
        asm volatile("s_waitcnt vmcnt(" #VM ")" ::: "memory"); \
        __builtin_amdgcn_sched_barrier(0); \
        __builtin_amdgcn_s_barrier()
#define PH_END_NW() \
        __builtin_amdgcn_s_setprio(0); \
        __builtin_amdgcn_sched_barrier(0); \
        __builtin_amdgcn_s_barrier()

    // prologue: B for tiles 0,1 (2-ahead), A for tile 0. Drain to the steady
    // invariant {A1_0, B0_1, B1_1} = vmcnt(6).
    STGB(0, 0, 0);
    STGB(0, 1, 0);
    STGA(0, 0, 0);
    STGA(0, 1, 0);
    STGB(1, 0, 1);
    STGB(1, 1, 1);
    asm volatile("s_waitcnt vmcnt(6)" ::: "memory");
    __builtin_amdgcn_s_barrier();

    int rA = 0;                       // A read buf (write = rA^1)
    int rB = 0, mB = 1, wB = 2;       // B bufs: read(t), t+1, write(t+2)
    #pragma unroll 1
    for (int t = 0; t < 32; ++t) {
        const int tA = (t + 1 < 32) ? (t + 1) : 31;   // clamp tail (redundant
        const int tB = (t + 2 < 32) ? (t + 2) : 31;   // stages keep counts uniform)
        const unsigned short* A0p = SMA(rA, 0);
        const unsigned short* A1p = SMA(rA, 1);
        const unsigned short* B0p = SMB(rB, 0);
        const unsigned short* B1p = SMB(rB, 1);
        // phase 0: Q(0,0); issue A0_{t+1}; no wait (all inputs pre-drained)
        RDA(A0p); RDB(b0f, B0p);
        STGA(rA ^ 1, 0, tA);
        PH_MID(); MM(0, 0, b0f); PH_END_NW();
        // phase 1: Q(0,1); issue A1_{t+1}; drain A1_t (needed ph2)
        RDB(b1f, B1p);
        STGA(rA ^ 1, 1, tA);
        PH_MID(); MM(0, 1, b1f); PH_END(8);
        // phase 2: Q(1,1); issue B0_{t+2}; no wait
        RDA(A1p);
        STGB(wB, 0, tB);
        PH_MID(); MM(1, 1, b1f); PH_END_NW();
        // phase 3: Q(1,0); issue B1_{t+2}; drain B0_{t+1},B1_{t+1},A0_{t+1}
        STGB(wB, 1, tB);
        PH_MID(); MM(1, 0, b0f); PH_END(6);
        // rotate buffers
        rA ^= 1;
        const int tmp = rB; rB = mB; mB = wB; wB = tmp;
    }
    asm volatile("s_waitcnt vmcnt(0)" ::: "memory");

    // epilogue: perm-bias + bf16 store (same semantics as mgemm EPI=2)
    const int crow = row0 + wm * 128 + quad * 4;
    const int ccol0 = col0 + wn * 64 + lm;
    #pragma unroll
    for (int ms = 0; ms < 8; ++ms)
        #pragma unroll
        for (int ns = 0; ns < 4; ++ns) {
            const int col = ccol0 + ns * 16;
            const float bv = bias[(col & 511) * 64 + (col >> 9)];
            #pragma unroll
            for (int r = 0; r < 4; ++r) {
                const int row = crow + ms * 16 + r;
                C[(long)row * 32768 + col] = f2bf(acc[ms][ns][r] + bv);
            }
        }
#undef SMA
#undef SMB
#undef STGA
#undef STGB
#undef RDA
#undef RDB
#undef MM
#undef PH_MID
#undef PH_END
#undef PH_END_NW
}

// ------------- fused lie-GEMM + 6-term Taylor matexp -> Gw (bf16) -------------
// Per block: b, j, 128 i's. lie[i,kl] = x_i . At[b,j,kl,:], M = xa - lie,
// Gamma = exp(M); Gw[b][k][i][j*8+l] = f2bf(aavg[b,i,j] * Gamma[k][l]).
// Grid (4, 512, 2), 256 threads. Taylor phase: M cached in 16 f32x4 regs
// (statically indexed), loaded once per pass -> 6x less LDS read traffic.
__global__ __launch_bounds__(256)
void liegamma_k(const unsigned short* __restrict__ xb, const unsigned short* __restrict__ At,
                const float* __restrict__ xa, const float* __restrict__ aavg,
                unsigned short* __restrict__ Gw)
{
    __shared__ unsigned short Xs[128][32];
    __shared__ unsigned short Ts[64][32];
    __shared__ float Ml[128][68];
    const int tid = threadIdx.x;
    const int wave = tid >> 6, lane = tid & 63;
    const int b = blockIdx.z, j = blockIdx.y;
    const int i0 = blockIdx.x * 128;
    const int lm = lane & 15, quad = lane >> 4;
    const int lrow = lane >> 2, lk = (lane & 3) * 8;
    const unsigned short* Xb = xb + ((long)b * 512 + i0) * 512;
    const unsigned short* Tb = At + ((long)(b * 512 + j)) * 32768;
    f32x4 acc[2][4];
    #pragma unroll
    for (int i = 0; i < 2; ++i)
        #pragma unroll
        for (int n = 0; n < 4; ++n) acc[i][n] = (f32x4)0.f;

    for (int k0 = 0; k0 < 512; k0 += 32) {
        #pragma unroll
        for (int t = 0; t < 2; ++t) {
            const int r = wave * 32 + t * 16;
            gload16(Xb + (long)(r + lrow) * 512 + k0 + lk, &Xs[r][0]);
        }
        {
            const int r = wave * 16;
            gload16(Tb + (long)(r + lrow) * 512 + k0 + lk, &Ts[r][0]);
        }
        __syncthreads();
        bf16x8 af[2], bfr[4];
        #pragma unroll
        for (int mt = 0; mt < 2; ++mt)
            af[mt] = *(const bf16x8*)&Xs[wave * 32 + mt * 16 + lm][quad * 8];
        #pragma unroll
        for (int nt = 0; nt < 4; ++nt)
            bfr[nt] = *(const bf16x8*)&Ts[nt * 16 + lm][quad * 8];
        #pragma unroll
        for (int mt = 0; mt < 2; ++mt)
            #pragma unroll
            for (int nt = 0; nt < 4; ++nt)
                acc[mt][nt] = __builtin_amdgcn_mfma_f32_16x16x32_bf16(
                    af[mt], bfr[nt], acc[mt][nt], 0, 0, 0);
        __syncthreads();
    }
    const float* xar = xa + ((long)(b * 512 + j)) * 64;
    #pragma unroll
    for (int mt = 0; mt < 2; ++mt)
        #pragma unroll
        for (int nt = 0; nt < 4; ++nt) {
            const float xv = xar[nt * 16 + lm];
            #pragma unroll
            for (int r = 0; r < 4; ++r)
                Ml[wave * 32 + mt * 16 + quad * 4 + r][nt * 16 + lm] = xv - acc[mt][nt][r];
        }
    __syncthreads();
    const int r8 = tid & 7, mg = tid >> 3;
    #pragma unroll 1
    for (int pass = 0; pass < 4; ++pass) {
        const int mi = pass * 32 + mg;
        const f32x4* Mr = (const f32x4*)&Ml[mi][0];
        f32x4 Mreg[16];
        #pragma unroll
        for (int l = 0; l < 16; ++l) Mreg[l] = Mr[l];
        float P[8], res[8];
        #pragma unroll
        for (int c = 0; c < 8; ++c) { const float iv = (c == r8) ? 1.f : 0.f; P[c] = iv; res[c] = iv; }
        #pragma unroll
        for (int n = 1; n <= 6; ++n) {
            float tmp[8] = {0.f,0.f,0.f,0.f,0.f,0.f,0.f,0.f};
            const float invn = 1.f / (float)n;
            #pragma unroll
            for (int l = 0; l < 8; ++l) {
                const f32x4 m0 = Mreg[l * 2], m1 = Mreg[l * 2 + 1];
                const float pl = P[l];
                #pragma unroll
                for (int c = 0; c < 4; ++c) {
                    tmp[c]     = fmaf(pl, m0[c], tmp[c]);
                    tmp[4 + c] = fmaf(pl, m1[c], tmp[4 + c]);
                }
            }
            #pragma unroll
            for (int c = 0; c < 8; ++c) { P[c] = tmp[c] * invn; res[c] += P[c]; }
        }
        const float av = aavg[((long)b * 512 + i0 + mi) * 512 + j];
        bf16x8 o;
        #pragma unroll
        for (int c = 0; c < 8; ++c) o[c] = (short)f2bf(res[c] * av);
        *(bf16x8*)(Gw + ((long)(b * 8 + r8) * 512 + (i0 + mi)) * 4096 + (long)j * 8) = o;
    }
}

// LayerNorm over last dim (2048) -> bf16 out. One block per row.
__global__ __launch_bounds__(256)
void lnbf_k(const float* __restrict__ h, const float* __restrict__ g,
            const float* __restrict__ b, unsigned short* __restrict__ out)
{
    const long row = blockIdx.x;
    const float* r = h + row * (long)DFF;
    const int tid = threadIdx.x;
    float vals[8];
    float s = 0.f, sq = 0.f;
    #pragma unroll
    for (int e = 0; e < 8; ++e) {
        const float v = r[tid + e * 256];
        vals[e] = v; s += v; sq += v * v;
    }
    __shared__ float rs[256], rq[256];
    rs[tid] = s; rq[tid] = sq; __syncthreads();
    for (int st = 128; st > 0; st >>= 1) {
        if (tid < st) { rs[tid] += rs[tid + st]; rq[tid] += rq[tid + st]; }
        __syncthreads();
    }
    const float mean = rs[0] * (1.f / DFF);
    const float var  = rq[0] * (1.f / DFF) - mean * mean;
    const float inv  = rsqrtf(var + 1e-5f);
    unsigned short* o = out + row * (long)DFF;
    #pragma unroll
    for (int e = 0; e < 8; ++e) {
        const int c = tid + e * 256;
        o[c] = f2bf((vals[e] - mean) * inv * g[c] + b[c]);
    }
}

// xa[bj,kl] = sum_d x[bj,d] * At[bj,kl,d]. 1024 blocks, 256 thr.
// Vectorized: bf16x8 At loads + f32x4 x loads, same accumulation order.
__global__ __launch_bounds__(256)
void xa_k(const float* __restrict__ x, const unsigned short* __restrict__ At,
          float* __restrict__ xa)
{
    const int bj = blockIdx.x;
    const int tid = threadIdx.x;
    const int kl = tid >> 2, q = tid & 3;
    const unsigned short* Ar = At + (long)bj * 32768 + kl * 512 + q * 128;
    const float* xr = x + (long)bj * 512 + q * 128;
    float s = 0.f;
    #pragma unroll
    for (int d0 = 0; d0 < 128; d0 += 8) {
        const bf16x8 a = *(const bf16x8*)&Ar[d0];
        const f32x4 x0 = *(const f32x4*)&xr[d0];
        const f32x4 x1 = *(const f32x4*)&xr[d0 + 4];
        s = fmaf(x0[0], bf2f((unsigned short)a[0]), s);
        s = fmaf(x0[1], bf2f((unsigned short)a[1]), s);
        s = fmaf(x0[2], bf2f((unsigned short)a[2]), s);
        s = fmaf(x0[3], bf2f((unsigned short)a[3]), s);
        s = fmaf(x1[0], bf2f((unsigned short)a[4]), s);
        s = fmaf(x1[1], bf2f((unsigned short)a[5]), s);
        s = fmaf(x1[2], bf2f((unsigned short)a[6]), s);
        s = fmaf(x1[3], bf2f((unsigned short)a[7]), s);
    }
    __shared__ float red[64][5];
    red[kl][q] = s; __syncthreads();
    if (q == 0)
        xa[(long)bj * 64 + kl] = red[kl][0] + red[kl][1] + red[kl][2] + red[kl][3];
}

// Softmax over last dim (512), in-place fp32 + bf16 copy.
__global__ __launch_bounds__(256)
void softmax_k(float* __restrict__ p, unsigned short* __restrict__ pb)
{
    const long row = blockIdx.x;
    float* r = p + row * 512;
    const int tid = threadIdx.x;
    float v0 = r[tid], v1 = r[tid + 256];
    __shared__ float red[256];
    red[tid] = fmaxf(v0, v1); __syncthreads();
    for (int s = 128; s > 0; s >>= 1) {
        if (tid < s) red[tid] = fmaxf(red[tid], red[tid + s]);
        __syncthreads();
    }
    const float m = red[0]; __syncthreads();
    v0 = expf(v0 - m); v1 = expf(v1 - m);
    red[tid] = v0 + v1; __syncthreads();
    for (int s = 128; s > 0; s >>= 1) {
        if (tid < s) red[tid] += red[tid + s];
        __syncthreads();
    }
    const float inv = 1.f / red[0];
    const float a0 = v0 * inv, a1 = v1 * inv;
    r[tid] = a0; r[tid + 256] = a1;
    unsigned short* rb = pb + row * 512;
    rb[tid] = f2bf(a0); rb[tid + 256] = f2bf(a1);
}

__global__ __launch_bounds__(256)
void aavg_k(const float* __restrict__ attn, float* __restrict__ aavg)
{
    const long idx = (long)blockIdx.x * 256 + threadIdx.x;
    const int b = (int)(idx >> 18);
    const long rem = idx & 262143;
    float s = 0.f;
    #pragma unroll
    for (int h = 0; h < HH; ++h)
        s += attn[(long)b * 2097152 + (long)h * 262144 + rem];
    aavg[idx] = s * 0.125f;
}

// [R][C] fp32 -> [C][R] bf16 transpose
__global__ __launch_bounds__(256)
void tconv_k(const float* __restrict__ in, unsigned short* __restrict__ out,
             int R, int C)
{
    __shared__ float Ls[64][65];
    const int c0 = blockIdx.x * 64, r0 = blockIdx.y * 64;
    const int tid = threadIdx.x;
    const int tc = tid & 63, tr = tid >> 6;
    #pragma unroll
    for (int p = 0; p < 16; ++p)
        Ls[tr + p * 4][tc] = in[(long)(r0 + tr + p * 4) * C + c0 + tc];
    __syncthreads();
    #pragma unroll
    for (int p = 0; p < 16; ++p)
        out[(long)(c0 + tr + p * 4) * R + r0 + tc] = f2bf(Ls[tc][tr + p * 4]);
}

// Wc2 [2048][32768] fp32 -> Wc2p [32768][2048] bf16: out[kl*512+d][f] = in[f][d*64+kl]
__global__ __launch_bounds__(256)
void wc2p_k(const float* __restrict__ in, unsigned short* __restrict__ out)
{
    __shared__ float Ls[64][65];
    const int d0 = blockIdx.x;
    const long f0 = blockIdx.y * 64;
    const int tid = threadIdx.x;
    const int tc = tid & 63, tr = tid >> 6;
    #pragma unroll
    for (int p = 0; p < 16; ++p)
        Ls[tr + p * 4][tc] = in[(f0 + tr + p * 4) * 32768 + (long)d0 * 64 + tc];
    __syncthreads();
    #pragma unroll
    for (int p = 0; p < 16; ++p) {
        const int kl = tr + p * 4;
        out[((long)kl * 512 + d0) * 2048 + f0 + tc] = f2bf(Ls[tc][kl]);
    }
}

__global__ __launch_bounds__(256)
void f2bf_k(const float* __restrict__ in, unsigned short* __restrict__ out, int n)
{
    const int i = blockIdx.x * 256 + threadIdx.x;
    if (i < n) out[i] = f2bf(in[i]);
}

extern "C" void kernel_launch(void* const* d_in, const int* in_sizes, int n_in,
                              void* d_out, int out_size, void* d_ws, size_t ws_size,
                              hipStream_t stream) {
    const float* x   = (const float*)d_in[0];
    const float* u   = (const float*)d_in[1];
    const float* Wq  = (const float*)d_in[2];  const float* bq  = (const float*)d_in[3];
    const float* Wk  = (const float*)d_in[4];  const float* bk  = (const float*)d_in[5];
    const float* Wv  = (const float*)d_in[6];  const float* bv  = (const float*)d_in[7];
    const float* Wo  = (const float*)d_in[8];  const float* bo  = (const float*)d_in[9];
    const float* Wfp = (const float*)d_in[10]; const float* bfp = (const float*)d_in[11];
    const float* Wfo = (const float*)d_in[12]; const float* bfo = (const float*)d_in[13];
    const float* Wc1 = (const float*)d_in[14]; const float* bc1 = (const float*)d_in[15];
    const float* gln = (const float*)d_in[16]; const float* bln = (const float*)d_in[17];
    const float* Wc2 = (const float*)d_in[18]; const float* bc2 = (const float*)d_in[19];

    float* ws = (float*)d_ws;
    // float-unit offsets; Gw aliases Wc2p (dead after fc2). Peak ~253 MB.
    unsigned short* Wc2p = (unsigned short*)(ws);                     // 33,554,432 fu
    unsigned short* Gw   = (unsigned short*)(ws);                     // alias
    unsigned short* At   = (unsigned short*)(ws + 33554432);          // 16,777,216 fu
    float*          h    = ws + 50331648;                             //  2,097,152 fu
    unsigned short* h_bf = (unsigned short*)(ws + 52428800);          //  1,048,576 fu
    unsigned short* x_bf = (unsigned short*)(ws + 53477376);          //    262,144 fu
    unsigned short* u_bf = (unsigned short*)(ws + 53739520);          //     32,768 fu
    unsigned short* Wc1t = (unsigned short*)(ws + 53772288);          //    524,288 fu
    unsigned short* Wqt  = (unsigned short*)(ws + 54296576);          //    131,072 fu
    unsigned short* Wkt  = (unsigned short*)(ws + 54427648);
    unsigned short* Wvt  = (unsigned short*)(ws + 54558720);
    unsigned short* Wot  = (unsigned short*)(ws + 54689792);
    unsigned short* Wfpt = (unsigned short*)(ws + 54820864);          //     16,384 fu
    unsigned short* Wfot = (unsigned short*)(ws + 54837248);          //     16,384 fu
    float*          xa   = ws + 54853632;                             //     65,536 fu
    unsigned short* q_bf = (unsigned short*)(ws + 54919168);          //    262,144 fu
    unsigned short* k_bf = (unsigned short*)(ws + 55181312);
    unsigned short* vT   = (unsigned short*)(ws + 55443456);
    float*          sc   = ws + 55705600;                             //  4,194,304 fu
    unsigned short* at_bf= (unsigned short*)(ws + 59899904);          //  2,097,152 fu
    float*          av   = ws + 61997056;                             //    524,288 fu
    unsigned short* ctx  = (unsigned short*)(ws + 62521344);          //    262,144 fu
    unsigned short* upT2 = (unsigned short*)(ws + 62783488);
    unsigned short* ut_bf= (unsigned short*)(ws + 63045632);
    float* xout = (float*)d_out;
    float* uout = xout + 524288;

    const dim3 blk(256);

    // fc2_k needs 160 KiB dynamic LDS: opt in (host-side, graph-capture safe)
    hipFuncSetAttribute(reinterpret_cast<const void*>(fc2_k),
                        hipFuncAttributeMaxDynamicSharedMemorySize, 163840);

    // --- conversions ---
    tconv_k<<<dim3(32, 8), blk, 0, stream>>>(Wc1, Wc1t, 512, 2048);
    tconv_k<<<dim3(8, 8), blk, 0, stream>>>(Wq, Wqt, 512, 512);
    tconv_k<<<dim3(8, 8), blk, 0, stream>>>(Wk, Wkt, 512, 512);
    tconv_k<<<dim3(8, 8), blk, 0, stream>>>(Wv, Wvt, 512, 512);
    tconv_k<<<dim3(8, 8), blk, 0, stream>>>(Wo, Wot, 512, 512);
    tconv_k<<<dim3(8, 1), blk, 0, stream>>>(Wfp, Wfpt, 64, 512);
    tconv_k<<<dim3(1, 8), blk, 0, stream>>>(Wfo, Wfot, 512, 64);
    wc2p_k<<<dim3(512, 32), blk, 0, stream>>>(Wc2, Wc2p);
    f2bf_k<<<dim3(2048), blk, 0, stream>>>(x, x_bf, 524288);
    f2bf_k<<<dim3(256), blk, 0, stream>>>(u, u_bf, 65536);

    // --- attention (bf16 MFMA) ---
    mgemm_k<128,3><<<dim3(4, 8, 1), blk, 0, stream>>>(
        x_bf, Wqt, bq, nullptr, nullptr, q_bf, 512, 512, 512, 512,
        1, 0,0,0,0,0,0, 1.0f);
    mgemm_k<128,3><<<dim3(4, 8, 1), blk, 0, stream>>>(
        x_bf, Wkt, bk, nullptr, nullptr, k_bf, 512, 512, 512, 512,
        1, 0,0,0,0,0,0, 1.0f);
    mgemm_k<128,5><<<dim3(4, 8, 1), blk, 0, stream>>>(
        x_bf, Wvt, bv, nullptr, nullptr, vT, 512, 512, 512, 512,
        1, 0,0,0,0,0,0, 1.0f);
    // scores = q.k^T/8, batched (b,h)
    mgemm_k<128,0><<<dim3(4, 4, 16), blk, 0, stream>>>(
        q_bf, k_bf, nullptr, nullptr, sc, nullptr, 64, 512, 512, 512,
        8, 262144,64, 262144,64, 2097152,262144, 0.125f);
    softmax_k<<<dim3(BB * HH * SS), blk, 0, stream>>>(sc, at_bf);
    aavg_k<<<dim3(2048), blk, 0, stream>>>(sc, av);
    // ctx = attn @ v, batched (b,h)
    mgemm_k<64,3><<<dim3(1, 4, 16), blk, 0, stream>>>(
        at_bf, vT, nullptr, nullptr, nullptr, ctx, 512, 512, 512, 512,
        8, 2097152,262144, 262144,32768, 262144,64, 1.0f);
    // x_out = x + ctx @ Wo + bo
    mgemm_k<128,4><<<dim3(4, 8, 1), blk, 0, stream>>>(
        ctx, Wot, bo, x, xout, nullptr, 512, 512, 512, 512,
        1, 0,0,0,0,0,0, 1.0f);

    // --- connection network ---
    mgemm_k<128,1><<<dim3(16, 8, 1), blk, 0, stream>>>(
        x_bf, Wc1t, bc1, nullptr, h, nullptr, 512, 512, 512, 2048,
        1, 0,0,0,0,0,0, 1.0f);
    lnbf_k<<<dim3(1024), blk, 0, stream>>>(h, gln, bln, h_bf);
    // fc2: 256x256-tile 8-wave pipelined GEMM, B triple-buffered (2 tiles deep)
    fc2_k<<<dim3(512), dim3(512), 163840, stream>>>(h_bf, Wc2p, bc2, At);
    xa_k<<<dim3(1024), blk, 0, stream>>>(x, At, xa);
    liegamma_k<<<dim3(4, 512, 2), blk, 0, stream>>>(x_bf, At, xa, av, Gw);

    // --- fiber transport ---
    mgemm_k<128,6><<<dim3(4, 8, 1), blk, 0, stream>>>(
        u_bf, Wfpt, bfp, nullptr, nullptr, upT2, 64, 64, 64, 512,
        1, 0,0,0,0,0,0, 1.0f);
    // ut[b,i,k*64+c] = Gw[b,k] @ upT2[b]^T, batched (b,k)
    mgemm_k<64,3><<<dim3(1, 4, 16), blk, 0, stream>>>(
        Gw, upT2, nullptr, nullptr, nullptr, ut_bf, 4096, 4096, 4096, 512,
        8, 16777216,2097152, 262144,0, 262144,64, 1.0f);
    // u_out = u + ut @ Wfo + bfo
    mgemm_k<64,4><<<dim3(1, 8, 1), blk, 0, stream>>>(
        ut_bf, Wfot, bfo, u, uout, nullptr, 512, 512, 512, 64,
        1, 0,0,0,0,0,0, 1.0f);
}

// Round 6
// 866.138 us; speedup vs baseline: 1.0900x; 1.0900x over previous
//
#include <hip/hip_runtime.h>
#include <math.h>

// B,S,D,K,DF,H,DFF = 2,512,512,8,64,8,2048
#define BB 2
#define SS 512
#define DD 512
#define HH 8
#define DFF 2048

typedef __attribute__((ext_vector_type(8))) short bf16x8;
typedef __attribute__((ext_vector_type(4))) float f32x4;

__device__ __forceinline__ float gelu_exact(float v) {
    return 0.5f * v * (1.0f + erff(v * 0.70710678118654752f));
}
__device__ __forceinline__ unsigned short f2bf(float f) {
    unsigned u = __float_as_uint(f);
    u += 0x7FFF + ((u >> 16) & 1);
    return (unsigned short)(u >> 16);
}
__device__ __forceinline__ float bf2f(unsigned short s) {
    return __uint_as_float(((unsigned)s) << 16);
}
__device__ __forceinline__ void gload16(const void* g, void* l) {
    __builtin_amdgcn_global_load_lds((const __attribute__((address_space(1))) void*)g,
                                     (__attribute__((address_space(3))) void*)l, 16, 0, 0);
}

// ---------------- flexible bf16 MFMA GEMM: C = epi(A @ B^T) ----------------
// A [M,K] bf16 (lda), B [N,K] bf16 (ldb, i.e. B^T layout). 128xNT tile, BK=32,
// 256 threads (4 waves 2x2), 16x16x32 MFMA. Batched over blockIdx.z.
// EPI: 0 fp32 out (scale, no bias) | 1 fp32 bias+gelu | 2 bf16 perm-bias (fc2)
//      3 bf16 out (+opt bias)      | 4 fp32 bias+resid | 5 bf16 vT-store
//      6 bf16 upT2-store           | 7 fp32 split-K partial (no bias):
//         Cf[z*cSB + chunk*cSH + row*ldc + col], chunk = blockIdx.x % SK.
template<int NT, int EPI, int SK = 1>
__global__ __launch_bounds__(256)
void mgemm_k(const unsigned short* __restrict__ A, const unsigned short* __restrict__ B,
             const float* __restrict__ bias, const float* __restrict__ resid,
             float* __restrict__ Cf, unsigned short* __restrict__ Cb,
             int K, int lda, int ldb, int ldc, int batchH,
             long aSB, long aSH, long bSB, long bSH, long cSB, long cSH,
             float scale)
{
    __shared__ unsigned short As[128][32];
    __shared__ unsigned short Bs[NT][32];
    const int tid = threadIdx.x;
    const int wave = tid >> 6, lane = tid & 63;
    const int z = blockIdx.z;
    const int zb = z / batchH, zh = z % batchH;
    const unsigned short* Ab = A + (long)zb * aSB + (long)zh * aSH;
    const unsigned short* Bb = B + (long)zb * bSB + (long)zh * bSH;
    const int chunk = (SK > 1) ? ((int)blockIdx.x % SK) : 0;
    const int colb  = (SK > 1) ? ((int)blockIdx.x / SK) : (int)blockIdx.x;
    const int row0 = blockIdx.y * 128, col0 = colb * NT;
    const int wm = wave >> 1, wn = wave & 1;
    const int lm = lane & 15, quad = lane >> 4;
    const int lrow = lane >> 2, lk = (lane & 3) * 8;
    constexpr int NTW = NT / 32;     // n-subtiles per wave
    f32x4 acc[4][NTW];
    #pragma unroll
    for (int i = 0; i < 4; ++i)
        #pragma unroll
        for (int j = 0; j < NTW; ++j) acc[i][j] = (f32x4)0.f;

    const int kLo = chunk * (K / SK), kHi = kLo + K / SK;
    for (int k0 = kLo; k0 < kHi; k0 += 32) {
        #pragma unroll
        for (int t = 0; t < 2; ++t) {
            const int r = wave * 32 + t * 16;
            gload16(Ab + (long)(row0 + r + lrow) * lda + k0 + lk, &As[r][0]);
        }
        if (NT == 128) {
            #pragma unroll
            for (int t = 0; t < 2; ++t) {
                const int r = wave * 32 + t * 16;
                gload16(Bb + (long)(col0 + r + lrow) * ldb + k0 + lk, &Bs[r][0]);
            }
        } else {
            const int r = wave * 16;
            gload16(Bb + (long)(col0 + r + lrow) * ldb + k0 + lk, &Bs[r][0]);
        }
        __syncthreads();
        bf16x8 af[4], bfr[NTW];
        #pragma unroll
        for (int mt = 0; mt < 4; ++mt)
            af[mt] = *(const bf16x8*)&As[wm * 64 + mt * 16 + lm][quad * 8];
        #pragma unroll
        for (int nt = 0; nt < NTW; ++nt)
            bfr[nt] = *(const bf16x8*)&Bs[wn * (NT / 2) + nt * 16 + lm][quad * 8];
        #pragma unroll
        for (int mt = 0; mt < 4; ++mt)
            #pragma unroll
            for (int nt = 0; nt < NTW; ++nt)
                acc[mt][nt] = __builtin_amdgcn_mfma_f32_16x16x32_bf16(
                    af[mt], bfr[nt], acc[mt][nt], 0, 0, 0);
        __syncthreads();
    }
    float* Cfz = (Cf && EPI != 7) ? Cf + (long)zb * cSB + (long)zh * cSH : Cf;
    unsigned short* Cbz = Cb ? Cb + (long)zb * cSB + (long)zh * cSH : nullptr;
    #pragma unroll
    for (int mt = 0; mt < 4; ++mt) {
        #pragma unroll
        for (int nt = 0; nt < NTW; ++nt) {
            #pragma unroll
            for (int r = 0; r < 4; ++r) {
                const int row = row0 + wm * 64 + mt * 16 + quad * 4 + r;
                const int col = col0 + wn * (NT / 2) + nt * 16 + lm;
                float v = acc[mt][nt][r] * scale;
                if (EPI == 2)      v += bias[(col & 511) * 64 + (col >> 9)];
                else if (EPI == 1 || EPI == 4) v += bias[col];
                else if ((EPI == 3 || EPI == 5 || EPI == 6) && bias) v += bias[col];
                if (EPI == 1) v = gelu_exact(v);
                if (EPI == 4) v += resid[(long)row * ldc + col];
                if (EPI == 0 || EPI == 1 || EPI == 4)
                    Cfz[(long)row * ldc + col] = v;
                else if (EPI == 7)  // split-K fp32 partial
                    Cf[(long)z * cSB + (long)chunk * cSH + (long)row * ldc + col] = v;
                else if (EPI == 2 || EPI == 3)
                    Cbz[(long)row * ldc + col] = f2bf(v);
                else if (EPI == 5)  // vT[b][h][c][j]: rows=(b,j), col=h*64+c
                    Cb[(long)(row >> 9) * 262144 + (col >> 6) * 32768 +
                       (col & 63) * 512 + (row & 511)] = f2bf(v);
                else if (EPI == 6)  // upT2[b][c][j*8+l]: rows=(b,j), col=l*64+c
                    Cb[(long)(row >> 9) * 262144 + (col & 63) * 4096 +
                       (row & 511) * 8 + (col >> 6)] = f2bf(v);
            }
        }
    }
}

// ---- split-K reduce kernels (fold EPI semantics over SK partials) ----
// q/k: out_bf16[1024][512] = Sigma + bias[col]
__global__ __launch_bounds__(256)
void redqk_k(const float* __restrict__ p, const float* __restrict__ bias,
             unsigned short* __restrict__ out)
{
    const long idx = (long)blockIdx.x * 256 + threadIdx.x;  // 524288
    const float s = p[idx] + p[idx + 524288] + p[idx + 1048576] + p[idx + 1572864]
                  + bias[idx & 511];
    out[idx] = f2bf(s);
}
// v: vT[b][h][c][j] scatter (EPI=5 semantics)
__global__ __launch_bounds__(256)
void redv_k(const float* __restrict__ p, const float* __restrict__ bias,
            unsigned short* __restrict__ vT)
{
    const long idx = (long)blockIdx.x * 256 + threadIdx.x;  // row*512+col
    const int col = (int)(idx & 511);
    const float s = p[idx] + p[idx + 524288] + p[idx + 1048576] + p[idx + 1572864]
                  + bias[col];
    vT[(idx >> 18) * 262144 + (col >> 6) * 32768 + (col & 63) * 512 +
       ((idx >> 9) & 511)] = f2bf(s);
}
// Wo: xout = x + bo + Sigma (EPI=4 semantics, fp32)
__global__ __launch_bounds__(256)
void redwo_k(const float* __restrict__ p, const float* __restrict__ bias,
             const float* __restrict__ resid, float* __restrict__ out)
{
    const long idx = (long)blockIdx.x * 256 + threadIdx.x;  // 524288
    out[idx] = resid[idx] + bias[idx & 511]
             + p[idx] + p[idx + 524288] + p[idx + 1048576] + p[idx + 1572864];
}
// ctx/ut: partial layout p[chunk][z=(b,zh)][i][c] -> out bf16 [b][i][zh*64+c]
template<int SK>
__global__ __launch_bounds__(256)
void redzc_k(const float* __restrict__ p, unsigned short* __restrict__ out)
{
    const long idx = (long)blockIdx.x * 256 + threadIdx.x;  // z*32768+i*64+c
    float s = 0.f;
    #pragma unroll
    for (int k = 0; k < SK; ++k) s += p[idx + (long)k * 524288];
    const int b = (int)(idx >> 18), zh = (int)((idx >> 15) & 7);
    const long rem = idx & 32767;
    const int i = (int)(rem >> 6), c = (int)(rem & 63);
    out[(long)b * 262144 + (long)i * 512 + zh * 64 + c] = f2bf(s);
}
// uout = u + bfo + Sigma (fp32, 65536 elems, chunk stride 65536)
__global__ __launch_bounds__(256)
void redu_k(const float* __restrict__ p, const float* __restrict__ bias,
            const float* __restrict__ resid, float* __restrict__ out)
{
    const long idx = (long)blockIdx.x * 256 + threadIdx.x;  // 65536
    out[idx] = resid[idx] + bias[idx & 63]
             + p[idx] + p[idx + 65536] + p[idx + 131072] + p[idx + 196608];
}

// ---------- fc2: 256x256-tile 8-wave 4-phase pipelined GEMM (T2+T3+T4+T5) ----------
// (unchanged from R5: A dbuf + B triple-buffered, 160 KiB LDS, vmcnt(8)/vmcnt(6))
__global__ __launch_bounds__(512, 2)
void fc2_k(const unsigned short* __restrict__ A, const unsigned short* __restrict__ Bm,
           const float* __restrict__ bias, unsigned short* __restrict__ C)
{
    extern __shared__ unsigned short smraw[];   // 81920 shorts = 160 KiB
#define SMA(ab, h) (smraw + (((ab) * 2 + (h)) * 8192))
#define SMB(bb, h) (smraw + (32768 + ((bb) * 2 + (h)) * 8192))
    const int tid = threadIdx.x;
    const int wave = tid >> 6, lane = tid & 63;
    const int bid = blockIdx.x;
    const int lin = (bid & 7) * 64 + (bid >> 3);
    const int by = lin & 3, bx = lin >> 2;
    const int row0 = by * 256, col0 = bx * 256;
    const int wm = wave >> 2, wn = wave & 3;          // 2 x 4 wave grid
    const int lm = lane & 15, quad = lane >> 4;
    const int axor = lm & 7;
    const int arow = (wm * 64 + lm) * 64;
    const int brow = (wn * 32 + lm) * 64;
    const int ca0 = ((quad) ^ axor) * 8;              // kk=0 chunk
    const int ca1 = ((quad + 4) ^ axor) * 8;          // kk=1 chunk
    const int srow = wave * 8 + (lane >> 3);          // local row r in [0,64)
    const int scx = ((lane & 7) ^ ((lane >> 3) & 7)) * 8;  // pre-swizzled source chunk
    const int sbrow = ((srow >> 5) << 6) + (srow & 31);    // B granule-interleave row
    const unsigned short* AgB = A + (long)(row0 + srow) * 2048 + scx;
    const unsigned short* BgB = Bm + (long)(col0 + sbrow) * 2048 + scx;

    f32x4 acc[8][4];
    #pragma unroll
    for (int i = 0; i < 8; ++i)
        #pragma unroll
        for (int j = 0; j < 4; ++j) acc[i][j] = (f32x4)0.f;
    bf16x8 afr[4][2], b0f[2][2], b1f[2][2];

#define STGA(ab, h, toff) do { \
        const unsigned short* _g = AgB + (toff) * 64 + (h) * (64 * 2048); \
        unsigned short* _d = SMA(ab, h) + wave * 512; \
        gload16(_g, _d); \
        gload16(_g + 128 * 2048, _d + 4096); \
    } while (0)
#define STGB(bb, h, toff) do { \
        const unsigned short* _g = BgB + (toff) * 64 + (h) * (32 * 2048); \
        unsigned short* _d = SMB(bb, h) + wave * 512; \
        gload16(_g, _d); \
        gload16(_g + 128 * 2048, _d + 4096); \
    } while (0)
#define RDA(Hp) do { _Pragma("unroll") for (int _m = 0; _m < 4; ++_m) { \
        afr[_m][0] = *(const bf16x8*)((Hp) + arow + _m * 1024 + ca0); \
        afr[_m][1] = *(const bf16x8*)((Hp) + arow + _m * 1024 + ca1); } } while (0)
#define RDB(bf, Hp) do { _Pragma("unroll") for (int _n = 0; _n < 2; ++_n) { \
        bf[_n][0] = *(const bf16x8*)((Hp) + brow + _n * 1024 + ca0); \
        bf[_n][1] = *(const bf16x8*)((Hp) + brow + _n * 1024 + ca1); } } while (0)
#define MM(QM, QN, bf) do { _Pragma("unroll") for (int _m = 0; _m < 4; ++_m) \
        _Pragma("unroll") for (int _n = 0; _n < 2; ++_n) { \
        acc[(QM)*4+_m][(QN)*2+_n] = __builtin_amdgcn_mfma_f32_16x16x32_bf16( \
            afr[_m][0], bf[_n][0], acc[(QM)*4+_m][(QN)*2+_n], 0, 0, 0); \
        acc[(QM)*4+_m][(QN)*2+_n] = __builtin_amdgcn_mfma_f32_16x16x32_bf16( \
            afr[_m][1], bf[_n][1], acc[(QM)*4+_m][(QN)*2+_n], 0, 0, 0); } } while (0)
#define PH_MID() \
        __builtin_amdgcn_s_barrier(); \
        asm volatile("s_waitcnt lgkmcnt(0)" ::: "memory"); \
        __builtin_amdgcn_sched_barrier(0); \
        __builtin_amdgcn_s_setprio(1)
#define PH_END(VM) \
        __builtin_amdgcn_s_setprio(0); \
        __builtin_amdgcn_sched_barrier(0); \
        asm volatile("s_waitcnt vmcnt(" #VM ")" ::: "memory"); \
        __builtin_amdgcn_sched_barrier(0); \
        __builtin_amdgcn_s_barrier()
#define PH_END_NW() \
        __builtin_amdgcn_s_setprio(0); \
        __builtin_amdgcn_sched_barrier(0); \
        __builtin_amdgcn_s_barrier()

    STGB(0, 0, 0);
    STGB(0, 1, 0);
    STGA(0, 0, 0);
    STGA(0, 1, 0);
    STGB(1, 0, 1);
    STGB(1, 1, 1);
    asm volatile("s_waitcnt vmcnt(6)" ::: "memory");
    __builtin_amdgcn_s_barrier();

    int rA = 0;
    int rB = 0, mB = 1, wB = 2;
    #pragma unroll 1
    for (int t = 0; t < 32; ++t) {
        const int tA = (t + 1 < 32) ? (t + 1) : 31;
        const int tB = (t + 2 < 32) ? (t + 2) : 31;
        const unsigned short* A0p = SMA(rA, 0);
        const unsigned short* A1p = SMA(rA, 1);
        const unsigned short* B0p = SMB(rB, 0);
        const unsigned short* B1p = SMB(rB, 1);
        RDA(A0p); RDB(b0f, B0p);
        STGA(rA ^ 1, 0, tA);
        PH_MID(); MM(0, 0, b0f); PH_END_NW();
        RDB(b1f, B1p);
        STGA(rA ^ 1, 1, tA);
        PH_MID(); MM(0, 1, b1f); PH_END(8);
        RDA(A1p);
        STGB(wB, 0, tB);
        PH_MID(); MM(1, 1, b1f); PH_END_NW();
        STGB(wB, 1, tB);
        PH_MID(); MM(1, 0, b0f); PH_END(6);
        rA ^= 1;
        const int tmp = rB; rB = mB; mB = wB; wB = tmp;
    }
    asm volatile("s_waitcnt vmcnt(0)" ::: "memory");

    const int crow = row0 + wm * 128 + quad * 4;
    const int ccol0 = col0 + wn * 64 + lm;
    #pragma unroll
    for (int ms = 0; ms < 8; ++ms)
        #pragma unroll
        for (int ns = 0; ns < 4; ++ns) {
            const int col = ccol0 + ns * 16;
            const float bv = bias[(col & 511) * 64 + (col >> 9)];
            #pragma unroll
            for (int r = 0; r < 4; ++r) {
                const int row = crow + ms * 16 + r;
                C[(long)row * 32768 + col] = f2bf(acc[ms][ns][r] + bv);
            }
        }
#undef SMA
#undef SMB
#undef STGA
#undef STGB
#undef RDA
#undef RDB
#undef MM
#undef PH_MID
#undef PH_END
#undef PH_END_NW
}

// ------------- fused lie-GEMM + 6-term Taylor matexp -> Gw (bf16) -------------
__global__ __launch_bounds__(256)
void liegamma_k(const unsigned short* __restrict__ xb, const unsigned short* __restrict__ At,
                const float* __restrict__ xa, const float* __restrict__ aavg,
                unsigned short* __restrict__ Gw)
{
    __shared__ unsigned short Xs[128][32];
    __shared__ unsigned short Ts[64][32];
    __shared__ float Ml[128][68];
    const int tid = threadIdx.x;
    const int wave = tid >> 6, lane = tid & 63;
    const int b = blockIdx.z, j = blockIdx.y;
    const int i0 = blockIdx.x * 128;
    const int lm = lane & 15, quad = lane >> 4;
    const int lrow = lane >> 2, lk = (lane & 3) * 8;
    const unsigned short* Xb = xb + ((long)b * 512 + i0) * 512;
    const unsigned short* Tb = At + ((long)(b * 512 + j)) * 32768;
    f32x4 acc[2][4];
    #pragma unroll
    for (int i = 0; i < 2; ++i)
        #pragma unroll
        for (int n = 0; n < 4; ++n) acc[i][n] = (f32x4)0.f;

    for (int k0 = 0; k0 < 512; k0 += 32) {
        #pragma unroll
        for (int t = 0; t < 2; ++t) {
            const int r = wave * 32 + t * 16;
            gload16(Xb + (long)(r + lrow) * 512 + k0 + lk, &Xs[r][0]);
        }
        {
            const int r = wave * 16;
            gload16(Tb + (long)(r + lrow) * 512 + k0 + lk, &Ts[r][0]);
        }
        __syncthreads();
        bf16x8 af[2], bfr[4];
        #pragma unroll
        for (int mt = 0; mt < 2; ++mt)
            af[mt] = *(const bf16x8*)&Xs[wave * 32 + mt * 16 + lm][quad * 8];
        #pragma unroll
        for (int nt = 0; nt < 4; ++nt)
            bfr[nt] = *(const bf16x8*)&Ts[nt * 16 + lm][quad * 8];
        #pragma unroll
        for (int mt = 0; mt < 2; ++mt)
            #pragma unroll
            for (int nt = 0; nt < 4; ++nt)
                acc[mt][nt] = __builtin_amdgcn_mfma_f32_16x16x32_bf16(
                    af[mt], bfr[nt], acc[mt][nt], 0, 0, 0);
        __syncthreads();
    }
    const float* xar = xa + ((long)(b * 512 + j)) * 64;
    #pragma unroll
    for (int mt = 0; mt < 2; ++mt)
        #pragma unroll
        for (int nt = 0; nt < 4; ++nt) {
            const float xv = xar[nt * 16 + lm];
            #pragma unroll
            for (int r = 0; r < 4; ++r)
                Ml[wave * 32 + mt * 16 + quad * 4 + r][nt * 16 + lm] = xv - acc[mt][nt][r];
        }
    __syncthreads();
    const int r8 = tid & 7, mg = tid >> 3;
    #pragma unroll 1
    for (int pass = 0; pass < 4; ++pass) {
        const int mi = pass * 32 + mg;
        const f32x4* Mr = (const f32x4*)&Ml[mi][0];
        f32x4 Mreg[16];
        #pragma unroll
        for (int l = 0; l < 16; ++l) Mreg[l] = Mr[l];
        float P[8], res[8];
        #pragma unroll
        for (int c = 0; c < 8; ++c) { const float iv = (c == r8) ? 1.f : 0.f; P[c] = iv; res[c] = iv; }
        #pragma unroll
        for (int n = 1; n <= 6; ++n) {
            float tmp[8] = {0.f,0.f,0.f,0.f,0.f,0.f,0.f,0.f};
            const float invn = 1.f / (float)n;
            #pragma unroll
            for (int l = 0; l < 8; ++l) {
                const f32x4 m0 = Mreg[l * 2], m1 = Mreg[l * 2 + 1];
                const float pl = P[l];
                #pragma unroll
                for (int c = 0; c < 4; ++c) {
                    tmp[c]     = fmaf(pl, m0[c], tmp[c]);
                    tmp[4 + c] = fmaf(pl, m1[c], tmp[4 + c]);
                }
            }
            #pragma unroll
            for (int c = 0; c < 8; ++c) { P[c] = tmp[c] * invn; res[c] += P[c]; }
        }
        const float av = aavg[((long)b * 512 + i0 + mi) * 512 + j];
        bf16x8 o;
        #pragma unroll
        for (int c = 0; c < 8; ++c) o[c] = (short)f2bf(res[c] * av);
        *(bf16x8*)(Gw + ((long)(b * 8 + r8) * 512 + (i0 + mi)) * 4096 + (long)j * 8) = o;
    }
}

// LayerNorm over last dim (2048) -> bf16 out. One block per row.
__global__ __launch_bounds__(256)
void lnbf_k(const float* __restrict__ h, const float* __restrict__ g,
            const float* __restrict__ b, unsigned short* __restrict__ out)
{
    const long row = blockIdx.x;
    const float* r = h + row * (long)DFF;
    const int tid = threadIdx.x;
    float vals[8];
    float s = 0.f, sq = 0.f;
    #pragma unroll
    for (int e = 0; e < 8; ++e) {
        const float v = r[tid + e * 256];
        vals[e] = v; s += v; sq += v * v;
    }
    __shared__ float rs[256], rq[256];
    rs[tid] = s; rq[tid] = sq; __syncthreads();
    for (int st = 128; st > 0; st >>= 1) {
        if (tid < st) { rs[tid] += rs[tid + st]; rq[tid] += rq[tid + st]; }
        __syncthreads();
    }
    const float mean = rs[0] * (1.f / DFF);
    const float var  = rq[0] * (1.f / DFF) - mean * mean;
    const float inv  = rsqrtf(var + 1e-5f);
    unsigned short* o = out + row * (long)DFF;
    #pragma unroll
    for (int e = 0; e < 8; ++e) {
        const int c = tid + e * 256;
        o[c] = f2bf((vals[e] - mean) * inv * g[c] + b[c]);
    }
}

// xa[bj,kl] = sum_d x[bj,d] * At[bj,kl,d]. 1024 blocks, 256 thr.
__global__ __launch_bounds__(256)
void xa_k(const float* __restrict__ x, const unsigned short* __restrict__ At,
          float* __restrict__ xa)
{
    const int bj = blockIdx.x;
    const int tid = threadIdx.x;
    const int kl = tid >> 2, q = tid & 3;
    const unsigned short* Ar = At + (long)bj * 32768 + kl * 512 + q * 128;
    const float* xr = x + (long)bj * 512 + q * 128;
    float s = 0.f;
    #pragma unroll
    for (int d0 = 0; d0 < 128; d0 += 8) {
        const bf16x8 a = *(const bf16x8*)&Ar[d0];
        const f32x4 x0 = *(const f32x4*)&xr[d0];
        const f32x4 x1 = *(const f32x4*)&xr[d0 + 4];
        s = fmaf(x0[0], bf2f((unsigned short)a[0]), s);
        s = fmaf(x0[1], bf2f((unsigned short)a[1]), s);
        s = fmaf(x0[2], bf2f((unsigned short)a[2]), s);
        s = fmaf(x0[3], bf2f((unsigned short)a[3]), s);
        s = fmaf(x1[0], bf2f((unsigned short)a[4]), s);
        s = fmaf(x1[1], bf2f((unsigned short)a[5]), s);
        s = fmaf(x1[2], bf2f((unsigned short)a[6]), s);
        s = fmaf(x1[3], bf2f((unsigned short)a[7]), s);
    }
    __shared__ float red[64][5];
    red[kl][q] = s; __syncthreads();
    if (q == 0)
        xa[(long)bj * 64 + kl] = red[kl][0] + red[kl][1] + red[kl][2] + red[kl][3];
}

// Softmax over last dim (512), in-place fp32 + bf16 copy.
__global__ __launch_bounds__(256)
void softmax_k(float* __restrict__ p, unsigned short* __restrict__ pb)
{
    const long row = blockIdx.x;
    float* r = p + row * 512;
    const int tid = threadIdx.x;
    float v0 = r[tid], v1 = r[tid + 256];
    __shared__ float red[256];
    red[tid] = fmaxf(v0, v1); __syncthreads();
    for (int s = 128; s > 0; s >>= 1) {
        if (tid < s) red[tid] = fmaxf(red[tid], red[tid + s]);
        __syncthreads();
    }
    const float m = red[0]; __syncthreads();
    v0 = expf(v0 - m); v1 = expf(v1 - m);
    red[tid] = v0 + v1; __syncthreads();
    for (int s = 128; s > 0; s >>= 1) {
        if (tid < s) red[tid] += red[tid + s];
        __syncthreads();
    }
    const float inv = 1.f / red[0];
    const float a0 = v0 * inv, a1 = v1 * inv;
    r[tid] = a0; r[tid + 256] = a1;
    unsigned short* rb = pb + row * 512;
    rb[tid] = f2bf(a0); rb[tid + 256] = f2bf(a1);
}

__global__ __launch_bounds__(256)
void aavg_k(const float* __restrict__ attn, float* __restrict__ aavg)
{
    const long idx = (long)blockIdx.x * 256 + threadIdx.x;
    const int b = (int)(idx >> 18);
    const long rem = idx & 262143;
    float s = 0.f;
    #pragma unroll
    for (int h = 0; h < HH; ++h)
        s += attn[(long)b * 2097152 + (long)h * 262144 + rem];
    aavg[idx] = s * 0.125f;
}

// [R][C] fp32 -> [C][R] bf16 transpose
__global__ __launch_bounds__(256)
void tconv_k(const float* __restrict__ in, unsigned short* __restrict__ out,
             int R, int C)
{
    __shared__ float Ls[64][65];
    const int c0 = blockIdx.x * 64, r0 = blockIdx.y * 64;
    const int tid = threadIdx.x;
    const int tc = tid & 63, tr = tid >> 6;
    #pragma unroll
    for (int p = 0; p < 16; ++p)
        Ls[tr + p * 4][tc] = in[(long)(r0 + tr + p * 4) * C + c0 + tc];
    __syncthreads();
    #pragma unroll
    for (int p = 0; p < 16; ++p)
        out[(long)(c0 + tr + p * 4) * R + r0 + tc] = f2bf(Ls[tc][tr + p * 4]);
}

// Wc2 [2048][32768] fp32 -> Wc2p [32768][2048] bf16: out[kl*512+d][f] = in[f][d*64+kl]
__global__ __launch_bounds__(256)
void wc2p_k(const float* __restrict__ in, unsigned short* __restrict__ out)
{
    __shared__ float Ls[64][65];
    const int d0 = blockIdx.x;
    const long f0 = blockIdx.y * 64;
    const int tid = threadIdx.x;
    const int tc = tid & 63, tr = tid >> 6;
    #pragma unroll
    for (int p = 0; p < 16; ++p)
        Ls[tr + p * 4][tc] = in[(f0 + tr + p * 4) * 32768 + (long)d0 * 64 + tc];
    __syncthreads();
    #pragma unroll
    for (int p = 0; p < 16; ++p) {
        const int kl = tr + p * 4;
        out[((long)kl * 512 + d0) * 2048 + f0 + tc] = f2bf(Ls[tc][kl]);
    }
}

__global__ __launch_bounds__(256)
void f2bf_k(const float* __restrict__ in, unsigned short* __restrict__ out, int n)
{
    const int i = blockIdx.x * 256 + threadIdx.x;
    if (i < n) out[i] = f2bf(in[i]);
}

extern "C" void kernel_launch(void* const* d_in, const int* in_sizes, int n_in,
                              void* d_out, int out_size, void* d_ws, size_t ws_size,
                              hipStream_t stream) {
    const float* x   = (const float*)d_in[0];
    const float* u   = (const float*)d_in[1];
    const float* Wq  = (const float*)d_in[2];  const float* bq  = (const float*)d_in[3];
    const float* Wk  = (const float*)d_in[4];  const float* bk  = (const float*)d_in[5];
    const float* Wv  = (const float*)d_in[6];  const float* bv  = (const float*)d_in[7];
    const float* Wo  = (const float*)d_in[8];  const float* bo  = (const float*)d_in[9];
    const float* Wfp = (const float*)d_in[10]; const float* bfp = (const float*)d_in[11];
    const float* Wfo = (const float*)d_in[12]; const float* bfo = (const float*)d_in[13];
    const float* Wc1 = (const float*)d_in[14]; const float* bc1 = (const float*)d_in[15];
    const float* gln = (const float*)d_in[16]; const float* bln = (const float*)d_in[17];
    const float* Wc2 = (const float*)d_in[18]; const float* bc2 = (const float*)d_in[19];

    float* ws = (float*)d_ws;
    // float-unit offsets; Gw aliases Wc2p (dead after fc2). Peak ~313 MB.
    unsigned short* Wc2p = (unsigned short*)(ws);                     // 33,554,432 fu
    unsigned short* Gw   = (unsigned short*)(ws);                     // alias
    unsigned short* At   = (unsigned short*)(ws + 33554432);          // 16,777,216 fu
    float*          h    = ws + 50331648;                             //  2,097,152 fu
    unsigned short* h_bf = (unsigned short*)(ws + 52428800);          //  1,048,576 fu
    unsigned short* x_bf = (unsigned short*)(ws + 53477376);          //    262,144 fu
    unsigned short* u_bf = (unsigned short*)(ws + 53739520);          //     32,768 fu
    unsigned short* Wc1t = (unsigned short*)(ws + 53772288);          //    524,288 fu
    unsigned short* Wqt  = (unsigned short*)(ws + 54296576);          //    131,072 fu
    unsigned short* Wkt  = (unsigned short*)(ws + 54427648);
    unsigned short* Wvt  = (unsigned short*)(ws + 54558720);
    unsigned short* Wot  = (unsigned short*)(ws + 54689792);
    unsigned short* Wfpt = (unsigned short*)(ws + 54820864);          //     16,384 fu
    unsigned short* Wfot = (unsigned short*)(ws + 54837248);          //     16,384 fu
    float*          xa   = ws + 54853632;                             //     65,536 fu
    unsigned short* q_bf = (unsigned short*)(ws + 54919168);          //    262,144 fu
    unsigned short* k_bf = (unsigned short*)(ws + 55181312);
    unsigned short* vT   = (unsigned short*)(ws + 55443456);
    float*          sc   = ws + 55705600;                             //  4,194,304 fu
    unsigned short* at_bf= (unsigned short*)(ws + 59899904);          //  2,097,152 fu
    float*          av   = ws + 61997056;                             //    524,288 fu
    unsigned short* ctx  = (unsigned short*)(ws + 62521344);          //    262,144 fu
    unsigned short* upT2 = (unsigned short*)(ws + 62783488);
    unsigned short* ut_bf= (unsigned short*)(ws + 63045632);
    // split-K fp32 partial buffers (beyond old 253 MB peak; ws is 1 GiB)
    float*          qp   = ws + 63307776;                             //  2,097,152 fu
    float*          kp   = ws + 65404928;
    float*          vp   = ws + 67502080;
    float*          wop  = ws + 69599232;
    float*          ctxp = ws + 71696384;
    float*          utp  = ws + 73793536;                             //  4,194,304 fu
    float*          up   = ws + 77987840;                             //    262,144 fu
    float* xout = (float*)d_out;
    float* uout = xout + 524288;

    const dim3 blk(256);

    // fc2_k needs 160 KiB dynamic LDS: opt in (host-side, graph-capture safe)
    hipFuncSetAttribute(reinterpret_cast<const void*>(fc2_k),
                        hipFuncAttributeMaxDynamicSharedMemorySize, 163840);

    // --- conversions ---
    tconv_k<<<dim3(32, 8), blk, 0, stream>>>(Wc1, Wc1t, 512, 2048);
    tconv_k<<<dim3(8, 8), blk, 0, stream>>>(Wq, Wqt, 512, 512);
    tconv_k<<<dim3(8, 8), blk, 0, stream>>>(Wk, Wkt, 512, 512);
    tconv_k<<<dim3(8, 8), blk, 0, stream>>>(Wv, Wvt, 512, 512);
    tconv_k<<<dim3(8, 8), blk, 0, stream>>>(Wo, Wot, 512, 512);
    tconv_k<<<dim3(8, 1), blk, 0, stream>>>(Wfp, Wfpt, 64, 512);
    tconv_k<<<dim3(1, 8), blk, 0, stream>>>(Wfo, Wfot, 512, 64);
    wc2p_k<<<dim3(512, 32), blk, 0, stream>>>(Wc2, Wc2p);
    f2bf_k<<<dim3(2048), blk, 0, stream>>>(x, x_bf, 524288);
    f2bf_k<<<dim3(256), blk, 0, stream>>>(u, u_bf, 65536);

    // --- attention (bf16 MFMA, split-K x4 on the projection GEMMs) ---
    mgemm_k<128,7,4><<<dim3(16, 8, 1), blk, 0, stream>>>(
        x_bf, Wqt, nullptr, nullptr, qp, nullptr, 512, 512, 512, 512,
        1, 0,0,0,0, 0,524288, 1.0f);
    redqk_k<<<dim3(2048), blk, 0, stream>>>(qp, bq, q_bf);
    mgemm_k<128,7,4><<<dim3(16, 8, 1), blk, 0, stream>>>(
        x_bf, Wkt, nullptr, nullptr, kp, nullptr, 512, 512, 512, 512,
        1, 0,0,0,0, 0,524288, 1.0f);
    redqk_k<<<dim3(2048), blk, 0, stream>>>(kp, bk, k_bf);
    mgemm_k<128,7,4><<<dim3(16, 8, 1), blk, 0, stream>>>(
        x_bf, Wvt, nullptr, nullptr, vp, nullptr, 512, 512, 512, 512,
        1, 0,0,0,0, 0,524288, 1.0f);
    redv_k<<<dim3(2048), blk, 0, stream>>>(vp, bv, vT);
    // scores = q.k^T/8, batched (b,h)
    mgemm_k<128,0><<<dim3(4, 4, 16), blk, 0, stream>>>(
        q_bf, k_bf, nullptr, nullptr, sc, nullptr, 64, 512, 512, 512,
        8, 262144,64, 262144,64, 2097152,262144, 0.125f);
    softmax_k<<<dim3(BB * HH * SS), blk, 0, stream>>>(sc, at_bf);
    aavg_k<<<dim3(2048), blk, 0, stream>>>(sc, av);
    // ctx = attn @ v, batched (b,h), split-K x4
    mgemm_k<64,7,4><<<dim3(4, 4, 16), blk, 0, stream>>>(
        at_bf, vT, nullptr, nullptr, ctxp, nullptr, 512, 512, 512, 64,
        8, 2097152,262144, 262144,32768, 32768,524288, 1.0f);
    redzc_k<4><<<dim3(2048), blk, 0, stream>>>(ctxp, ctx);
    // x_out = x + ctx @ Wo + bo, split-K x4
    mgemm_k<128,7,4><<<dim3(16, 8, 1), blk, 0, stream>>>(
        ctx, Wot, nullptr, nullptr, wop, nullptr, 512, 512, 512, 512,
        1, 0,0,0,0, 0,524288, 1.0f);
    redwo_k<<<dim3(2048), blk, 0, stream>>>(wop, bo, x, xout);

    // --- connection network ---
    mgemm_k<128,1><<<dim3(16, 8, 1), blk, 0, stream>>>(
        x_bf, Wc1t, bc1, nullptr, h, nullptr, 512, 512, 512, 2048,
        1, 0,0,0,0,0,0, 1.0f);
    lnbf_k<<<dim3(1024), blk, 0, stream>>>(h, gln, bln, h_bf);
    // fc2: 256x256-tile 8-wave pipelined GEMM, B triple-buffered (2 tiles deep)
    fc2_k<<<dim3(512), dim3(512), 163840, stream>>>(h_bf, Wc2p, bc2, At);
    xa_k<<<dim3(1024), blk, 0, stream>>>(x, At, xa);
    liegamma_k<<<dim3(4, 512, 2), blk, 0, stream>>>(x_bf, At, xa, av, Gw);

    // --- fiber transport ---
    mgemm_k<128,6><<<dim3(4, 8, 1), blk, 0, stream>>>(
        u_bf, Wfpt, bfp, nullptr, nullptr, upT2, 64, 64, 64, 512,
        1, 0,0,0,0,0,0, 1.0f);
    // ut[b,i,k*64+c] = Gw[b,k] @ upT2[b]^T, batched (b,k), split-K x8
    mgemm_k<64,7,8><<<dim3(8, 4, 16), blk, 0, stream>>>(
        Gw, upT2, nullptr, nullptr, utp, nullptr, 4096, 4096, 4096, 64,
        8, 16777216,2097152, 262144,0, 32768,524288, 1.0f);
    redzc_k<8><<<dim3(2048), blk, 0, stream>>>(utp, ut_bf);
    // u_out = u + ut @ Wfo + bfo, split-K x4
    mgemm_k<64,7,4><<<dim3(4, 8, 1), blk, 0, stream>>>(
        ut_bf, Wfot, nullptr, nullptr, up, nullptr, 512, 512, 512, 64,
        1, 0,0,0,0, 0,65536, 1.0f);
    redu_k<<<dim3(256), blk, 0, stream>>>(up, bfo, u, uout);
}

// Round 7
// 822.947 us; speedup vs baseline: 1.1472x; 1.0525x over previous
//
#include <hip/hip_runtime.h>
#include <math.h>

// B,S,D,K,DF,H,DFF = 2,512,512,8,64,8,2048
#define BB 2
#define SS 512
#define DD 512
#define HH 8
#define DFF 2048

typedef __attribute__((ext_vector_type(8))) short bf16x8;
typedef __attribute__((ext_vector_type(4))) float f32x4;

__device__ __forceinline__ float gelu_exact(float v) {
    return 0.5f * v * (1.0f + erff(v * 0.70710678118654752f));
}
__device__ __forceinline__ unsigned short f2bf(float f) {
    unsigned u = __float_as_uint(f);
    u += 0x7FFF + ((u >> 16) & 1);
    return (unsigned short)(u >> 16);
}
__device__ __forceinline__ float bf2f(unsigned short s) {
    return __uint_as_float(((unsigned)s) << 16);
}
__device__ __forceinline__ void gload16(const void* g, void* l) {
    __builtin_amdgcn_global_load_lds((const __attribute__((address_space(1))) void*)g,
                                     (__attribute__((address_space(3))) void*)l, 16, 0, 0);
}

// ---------------- flexible bf16 MFMA GEMM: C = epi(A @ B^T) ----------------
// A [M,K] bf16 (lda), B [N,K] bf16 (ldb, i.e. B^T layout). 128xNT tile, BK=32,
// 256 threads (4 waves 2x2), 16x16x32 MFMA. Batched over blockIdx.z.
// EPI: 0 fp32 out (scale, no bias) | 1 fp32 bias+gelu | 2 bf16 perm-bias (fc2)
//      3 bf16 out (+opt bias)      | 4 fp32 bias+resid | 5 bf16 vT-store
//      6 bf16 upT2-store           | 7 fp32 split-K partial (no bias):
//         Cf[z*cSB + chunk*cSH + row*ldc + col], chunk = blockIdx.x % SK.
template<int NT, int EPI, int SK = 1>
__global__ __launch_bounds__(256)
void mgemm_k(const unsigned short* __restrict__ A, const unsigned short* __restrict__ B,
             const float* __restrict__ bias, const float* __restrict__ resid,
             float* __restrict__ Cf, unsigned short* __restrict__ Cb,
             int K, int lda, int ldb, int ldc, int batchH,
             long aSB, long aSH, long bSB, long bSH, long cSB, long cSH,
             float scale)
{
    __shared__ unsigned short As[128][32];
    __shared__ unsigned short Bs[NT][32];
    const int tid = threadIdx.x;
    const int wave = tid >> 6, lane = tid & 63;
    const int z = blockIdx.z;
    const int zb = z / batchH, zh = z % batchH;
    const unsigned short* Ab = A + (long)zb * aSB + (long)zh * aSH;
    const unsigned short* Bb = B + (long)zb * bSB + (long)zh * bSH;
    const int chunk = (SK > 1) ? ((int)blockIdx.x % SK) : 0;
    const int colb  = (SK > 1) ? ((int)blockIdx.x / SK) : (int)blockIdx.x;
    const int row0 = blockIdx.y * 128, col0 = colb * NT;
    const int wm = wave >> 1, wn = wave & 1;
    const int lm = lane & 15, quad = lane >> 4;
    const int lrow = lane >> 2, lk = (lane & 3) * 8;
    constexpr int NTW = NT / 32;     // n-subtiles per wave
    f32x4 acc[4][NTW];
    #pragma unroll
    for (int i = 0; i < 4; ++i)
        #pragma unroll
        for (int j = 0; j < NTW; ++j) acc[i][j] = (f32x4)0.f;

    const int kLo = chunk * (K / SK), kHi = kLo + K / SK;
    for (int k0 = kLo; k0 < kHi; k0 += 32) {
        #pragma unroll
        for (int t = 0; t < 2; ++t) {
            const int r = wave * 32 + t * 16;
            gload16(Ab + (long)(row0 + r + lrow) * lda + k0 + lk, &As[r][0]);
        }
        if (NT == 128) {
            #pragma unroll
            for (int t = 0; t < 2; ++t) {
                const int r = wave * 32 + t * 16;
                gload16(Bb + (long)(col0 + r + lrow) * ldb + k0 + lk, &Bs[r][0]);
            }
        } else {
            const int r = wave * 16;
            gload16(Bb + (long)(col0 + r + lrow) * ldb + k0 + lk, &Bs[r][0]);
        }
        __syncthreads();
        bf16x8 af[4], bfr[NTW];
        #pragma unroll
        for (int mt = 0; mt < 4; ++mt)
            af[mt] = *(const bf16x8*)&As[wm * 64 + mt * 16 + lm][quad * 8];
        #pragma unroll
        for (int nt = 0; nt < NTW; ++nt)
            bfr[nt] = *(const bf16x8*)&Bs[wn * (NT / 2) + nt * 16 + lm][quad * 8];
        #pragma unroll
        for (int mt = 0; mt < 4; ++mt)
            #pragma unroll
            for (int nt = 0; nt < NTW; ++nt)
                acc[mt][nt] = __builtin_amdgcn_mfma_f32_16x16x32_bf16(
                    af[mt], bfr[nt], acc[mt][nt], 0, 0, 0);
        __syncthreads();
    }
    float* Cfz = (Cf && EPI != 7) ? Cf + (long)zb * cSB + (long)zh * cSH : Cf;
    unsigned short* Cbz = Cb ? Cb + (long)zb * cSB + (long)zh * cSH : nullptr;
    #pragma unroll
    for (int mt = 0; mt < 4; ++mt) {
        #pragma unroll
        for (int nt = 0; nt < NTW; ++nt) {
            #pragma unroll
            for (int r = 0; r < 4; ++r) {
                const int row = row0 + wm * 64 + mt * 16 + quad * 4 + r;
                const int col = col0 + wn * (NT / 2) + nt * 16 + lm;
                float v = acc[mt][nt][r] * scale;
                if (EPI == 2)      v += bias[(col & 511) * 64 + (col >> 9)];
                else if (EPI == 1 || EPI == 4) v += bias[col];
                else if ((EPI == 3 || EPI == 5 || EPI == 6) && bias) v += bias[col];
                if (EPI == 1) v = gelu_exact(v);
                if (EPI == 4) v += resid[(long)row * ldc + col];
                if (EPI == 0 || EPI == 1 || EPI == 4)
                    Cfz[(long)row * ldc + col] = v;
                else if (EPI == 7)  // split-K fp32 partial
                    Cf[(long)z * cSB + (long)chunk * cSH + (long)row * ldc + col] = v;
                else if (EPI == 2 || EPI == 3)
                    Cbz[(long)row * ldc + col] = f2bf(v);
                else if (EPI == 5)  // vT[b][h][c][j]: rows=(b,j), col=h*64+c
                    Cb[(long)(row >> 9) * 262144 + (col >> 6) * 32768 +
                       (col & 63) * 512 + (row & 511)] = f2bf(v);
                else if (EPI == 6)  // upT2[b][c][j*8+l]: rows=(b,j), col=l*64+c
                    Cb[(long)(row >> 9) * 262144 + (col & 63) * 4096 +
                       (row & 511) * 8 + (col >> 6)] = f2bf(v);
            }
        }
    }
}

// ---- split-K reduce kernels (fold EPI semantics over SK partials) ----
// fused QKV reduce: p[4][1024][1536]; col segment 0=q,1=k,2=v. grid (6,1024).
__global__ __launch_bounds__(256)
void redqkv_k(const float* __restrict__ p, const float* __restrict__ bq,
              const float* __restrict__ bk, const float* __restrict__ bv,
              unsigned short* __restrict__ q_bf, unsigned short* __restrict__ k_bf,
              unsigned short* __restrict__ vT)
{
    const int col = blockIdx.x * 256 + threadIdx.x;   // [0,1536)
    const int row = blockIdx.y;                        // [0,1024)
    const long base = (long)row * 1536 + col;
    float s = p[base] + p[base + 1572864] + p[base + 3145728] + p[base + 4718592];
    const int which = col >> 9;       // uniform per block (256 | 512)
    const int scol = col & 511;
    if (which == 0) {
        q_bf[(long)row * 512 + scol] = f2bf(s + bq[scol]);
    } else if (which == 1) {
        k_bf[(long)row * 512 + scol] = f2bf(s + bk[scol]);
    } else {
        s += bv[scol];
        vT[(long)(row >> 9) * 262144 + (scol >> 6) * 32768 +
           (scol & 63) * 512 + (row & 511)] = f2bf(s);
    }
}
// Wo: xout = x + bo + Sigma (EPI=4 semantics, fp32)
__global__ __launch_bounds__(256)
void redwo_k(const float* __restrict__ p, const float* __restrict__ bias,
             const float* __restrict__ resid, float* __restrict__ out)
{
    const long idx = (long)blockIdx.x * 256 + threadIdx.x;  // 524288
    out[idx] = resid[idx] + bias[idx & 511]
             + p[idx] + p[idx + 524288] + p[idx + 1048576] + p[idx + 1572864];
}
// ctx/ut: partial layout p[chunk][z=(b,zh)][i][c] -> out bf16 [b][i][zh*64+c]
template<int SK>
__global__ __launch_bounds__(256)
void redzc_k(const float* __restrict__ p, unsigned short* __restrict__ out)
{
    const long idx = (long)blockIdx.x * 256 + threadIdx.x;  // z*32768+i*64+c
    float s = 0.f;
    #pragma unroll
    for (int k = 0; k < SK; ++k) s += p[idx + (long)k * 524288];
    const int b = (int)(idx >> 18), zh = (int)((idx >> 15) & 7);
    const long rem = idx & 32767;
    const int i = (int)(rem >> 6), c = (int)(rem & 63);
    out[(long)b * 262144 + (long)i * 512 + zh * 64 + c] = f2bf(s);
}
// uout = u + bfo + Sigma (fp32, 65536 elems, chunk stride 65536)
__global__ __launch_bounds__(256)
void redu_k(const float* __restrict__ p, const float* __restrict__ bias,
            const float* __restrict__ resid, float* __restrict__ out)
{
    const long idx = (long)blockIdx.x * 256 + threadIdx.x;  // 65536
    out[idx] = resid[idx] + bias[idx & 63]
             + p[idx] + p[idx + 65536] + p[idx + 131072] + p[idx + 196608];
}

// ---------- fc2: 256x256-tile 8-wave 4-phase pipelined GEMM (T2+T3+T4+T5) ----------
// (A dbuf + B triple-buffered, 160 KiB LDS, counted vmcnt(8)/vmcnt(6))
__global__ __launch_bounds__(512, 2)
void fc2_k(const unsigned short* __restrict__ A, const unsigned short* __restrict__ Bm,
           const float* __restrict__ bias, unsigned short* __restrict__ C)
{
    extern __shared__ unsigned short smraw[];   // 81920 shorts = 160 KiB
#define SMA(ab, h) (smraw + (((ab) * 2 + (h)) * 8192))
#define SMB(bb, h) (smraw + (32768 + ((bb) * 2 + (h)) * 8192))
    const int tid = threadIdx.x;
    const int wave = tid >> 6, lane = tid & 63;
    const int bid = blockIdx.x;
    const int lin = (bid & 7) * 64 + (bid >> 3);
    const int by = lin & 3, bx = lin >> 2;
    const int row0 = by * 256, col0 = bx * 256;
    const int wm = wave >> 2, wn = wave & 3;          // 2 x 4 wave grid
    const int lm = lane & 15, quad = lane >> 4;
    const int axor = lm & 7;
    const int arow = (wm * 64 + lm) * 64;
    const int brow = (wn * 32 + lm) * 64;
    const int ca0 = ((quad) ^ axor) * 8;              // kk=0 chunk
    const int ca1 = ((quad + 4) ^ axor) * 8;          // kk=1 chunk
    const int srow = wave * 8 + (lane >> 3);          // local row r in [0,64)
    const int scx = ((lane & 7) ^ ((lane >> 3) & 7)) * 8;  // pre-swizzled source chunk
    const int sbrow = ((srow >> 5) << 6) + (srow & 31);    // B granule-interleave row
    const unsigned short* AgB = A + (long)(row0 + srow) * 2048 + scx;
    const unsigned short* BgB = Bm + (long)(col0 + sbrow) * 2048 + scx;

    f32x4 acc[8][4];
    #pragma unroll
    for (int i = 0; i < 8; ++i)
        #pragma unroll
        for (int j = 0; j < 4; ++j) acc[i][j] = (f32x4)0.f;
    bf16x8 afr[4][2], b0f[2][2], b1f[2][2];

#define STGA(ab, h, toff) do { \
        const unsigned short* _g = AgB + (toff) * 64 + (h) * (64 * 2048); \
        unsigned short* _d = SMA(ab, h) + wave * 512; \
        gload16(_g, _d); \
        gload16(_g + 128 * 2048, _d + 4096); \
    } while (0)
#define STGB(bb, h, toff) do { \
        const unsigned short* _g = BgB + (toff) * 64 + (h) * (32 * 2048); \
        unsigned short* _d = SMB(bb, h) + wave * 512; \
        gload16(_g, _d); \
        gload16(_g + 128 * 2048, _d + 4096); \
    } while (0)
#define RDA(Hp) do { _Pragma("unroll") for (int _m = 0; _m < 4; ++_m) { \
        afr[_m][0] = *(const bf16x8*)((Hp) + arow + _m * 1024 + ca0); \
        afr[_m][1] = *(const bf16x8*)((Hp) + arow + _m * 1024 + ca1); } } while (0)
#define RDB(bf, Hp) do { _Pragma("unroll") for (int _n = 0; _n < 2; ++_n) { \
        bf[_n][0] = *(const bf16x8*)((Hp) + brow + _n * 1024 + ca0); \
        bf[_n][1] = *(const bf16x8*)((Hp) + brow + _n * 1024 + ca1); } } while (0)
#define MM(QM, QN, bf) do { _Pragma("unroll") for (int _m = 0; _m < 4; ++_m) \
        _Pragma("unroll") for (int _n = 0; _n < 2; ++_n) { \
        acc[(QM)*4+_m][(QN)*2+_n] = __builtin_amdgcn_mfma_f32_16x16x32_bf16( \
            afr[_m][0], bf[_n][0], acc[(QM)*4+_m][(QN)*2+_n], 0, 0, 0); \
        acc[(QM)*4+_m][(QN)*2+_n] = __builtin_amdgcn_mfma_f32_16x16x32_bf16( \
            afr[_m][1], bf[_n][1], acc[(QM)*4+_m][(QN)*2+_n], 0, 0, 0); } } while (0)
#define PH_MID() \
        __builtin_amdgcn_s_barrier(); \
        asm volatile("s_waitcnt lgkmcnt(0)" ::: "memory"); \
        __builtin_amdgcn_sched_barrier(0); \
        __builtin_amdgcn_s_setprio(1)
#define PH_END(VM) \
        __builtin_amdgcn_s_setprio(0); \
        __builtin_amdgcn_sched_barrier(0); \
        asm volatile("s_waitcnt vmcnt(" #VM ")" ::: "memory"); \
        __builtin_amdgcn_sched_barrier(0); \
        __builtin_amdgcn_s_barrier()
#define PH_END_NW() \
        __builtin_amdgcn_s_setprio(0); \
        __builtin_amdgcn_sched_barrier(0); \
        __builtin_amdgcn_s_barrier()

    STGB(0, 0, 0);
    STGB(0, 1, 0);
    STGA(0, 0, 0);
    STGA(0, 1, 0);
    STGB(1, 0, 1);
    STGB(1, 1, 1);
    asm volatile("s_waitcnt vmcnt(6)" ::: "memory");
    __builtin_amdgcn_s_barrier();

    int rA = 0;
    int rB = 0, mB = 1, wB = 2;
    #pragma unroll 1
    for (int t = 0; t < 32; ++t) {
        const int tA = (t + 1 < 32) ? (t + 1) : 31;
        const int tB = (t + 2 < 32) ? (t + 2) : 31;
        const unsigned short* A0p = SMA(rA, 0);
        const unsigned short* A1p = SMA(rA, 1);
        const unsigned short* B0p = SMB(rB, 0);
        const unsigned short* B1p = SMB(rB, 1);
        RDA(A0p); RDB(b0f, B0p);
        STGA(rA ^ 1, 0, tA);
        PH_MID(); MM(0, 0, b0f); PH_END_NW();
        RDB(b1f, B1p);
        STGA(rA ^ 1, 1, tA);
        PH_MID(); MM(0, 1, b1f); PH_END(8);
        RDA(A1p);
        STGB(wB, 0, tB);
        PH_MID(); MM(1, 1, b1f); PH_END_NW();
        STGB(wB, 1, tB);
        PH_MID(); MM(1, 0, b0f); PH_END(6);
        rA ^= 1;
        const int tmp = rB; rB = mB; mB = wB; wB = tmp;
    }
    asm volatile("s_waitcnt vmcnt(0)" ::: "memory");

    const int crow = row0 + wm * 128 + quad * 4;
    const int ccol0 = col0 + wn * 64 + lm;
    #pragma unroll
    for (int ms = 0; ms < 8; ++ms)
        #pragma unroll
        for (int ns = 0; ns < 4; ++ns) {
            const int col = ccol0 + ns * 16;
            const float bv = bias[(col & 511) * 64 + (col >> 9)];
            #pragma unroll
            for (int r = 0; r < 4; ++r) {
                const int row = crow + ms * 16 + r;
                C[(long)row * 32768 + col] = f2bf(acc[ms][ns][r] + bv);
            }
        }
#undef SMA
#undef SMB
#undef STGA
#undef STGB
#undef RDA
#undef RDB
#undef MM
#undef PH_MID
#undef PH_END
#undef PH_END_NW
}

// ------------- fused lie-GEMM + xa + 6-term Taylor matexp -> Gw (bf16) -------------
// Per block: b, j, 128 i's. lie[i,kl] = x_i . At[b,j,kl,:], xa[kl] = x_j . At[b,j,kl,:]
// (computed in-kernel from the Ts tiles, replacing the separate xa_k pass),
// M = xa - lie, Gamma = exp(M); Gw[b][k][i][j*8+l] = f2bf(aavg[b,i,j]*Gamma[k][l]).
// Grid (4, 512, 2), 256 threads.
__global__ __launch_bounds__(256)
void liegamma_k(const unsigned short* __restrict__ xb, const unsigned short* __restrict__ At,
                const float* __restrict__ xf, const float* __restrict__ aavg,
                unsigned short* __restrict__ Gw)
{
    __shared__ unsigned short Xs[128][32];
    __shared__ unsigned short Ts[64][32];
    __shared__ float Ml[128][68];
    __shared__ float xjs[512];
    __shared__ float xred[64][4];
    __shared__ float xafin[64];
    const int tid = threadIdx.x;
    const int wave = tid >> 6, lane = tid & 63;
    const int b = blockIdx.z, j = blockIdx.y;
    const int i0 = blockIdx.x * 128;
    const int lm = lane & 15, quad = lane >> 4;
    const int lrow = lane >> 2, lk = (lane & 3) * 8;
    const unsigned short* Xb = xb + ((long)b * 512 + i0) * 512;
    const unsigned short* Tb = At + ((long)(b * 512 + j)) * 32768;
    // x_j row (fp32) into LDS once
    const float* xrow = xf + ((long)b * 512 + j) * 512;
    xjs[tid] = xrow[tid];
    xjs[tid + 256] = xrow[tid + 256];
    f32x4 acc[2][4];
    #pragma unroll
    for (int i = 0; i < 2; ++i)
        #pragma unroll
        for (int n = 0; n < 4; ++n) acc[i][n] = (f32x4)0.f;
    float xas = 0.f;
    const int kl2 = tid >> 2, q2 = tid & 3;

    for (int k0 = 0; k0 < 512; k0 += 32) {
        #pragma unroll
        for (int t = 0; t < 2; ++t) {
            const int r = wave * 32 + t * 16;
            gload16(Xb + (long)(r + lrow) * 512 + k0 + lk, &Xs[r][0]);
        }
        {
            const int r = wave * 16;
            gload16(Tb + (long)(r + lrow) * 512 + k0 + lk, &Ts[r][0]);
        }
        __syncthreads();
        bf16x8 af[2], bfr[4];
        #pragma unroll
        for (int mt = 0; mt < 2; ++mt)
            af[mt] = *(const bf16x8*)&Xs[wave * 32 + mt * 16 + lm][quad * 8];
        #pragma unroll
        for (int nt = 0; nt < 4; ++nt)
            bfr[nt] = *(const bf16x8*)&Ts[nt * 16 + lm][quad * 8];
        #pragma unroll
        for (int mt = 0; mt < 2; ++mt)
            #pragma unroll
            for (int nt = 0; nt < 4; ++nt)
                acc[mt][nt] = __builtin_amdgcn_mfma_f32_16x16x32_bf16(
                    af[mt], bfr[nt], acc[mt][nt], 0, 0, 0);
        // xa partial: thread (kl2,q2) covers Ts[kl2][q2*8 .. q2*8+7]
        {
            const bf16x8 tv = *(const bf16x8*)&Ts[kl2][q2 * 8];
            const float* xs = &xjs[k0 + q2 * 8];
            #pragma unroll
            for (int e = 0; e < 8; ++e)
                xas = fmaf(xs[e], bf2f((unsigned short)tv[e]), xas);
        }
        __syncthreads();
    }
    // reduce xa partials: xafin[kl] = sum over 4 q-chunks
    xred[kl2][q2] = xas;
    __syncthreads();
    if (tid < 64)
        xafin[tid] = xred[tid][0] + xred[tid][1] + xred[tid][2] + xred[tid][3];
    __syncthreads();
    #pragma unroll
    for (int mt = 0; mt < 2; ++mt)
        #pragma unroll
        for (int nt = 0; nt < 4; ++nt) {
            const float xv = xafin[nt * 16 + lm];
            #pragma unroll
            for (int r = 0; r < 4; ++r)
                Ml[wave * 32 + mt * 16 + quad * 4 + r][nt * 16 + lm] = xv - acc[mt][nt][r];
        }
    __syncthreads();
    const int r8 = tid & 7, mg = tid >> 3;
    #pragma unroll 1
    for (int pass = 0; pass < 4; ++pass) {
        const int mi = pass * 32 + mg;
        const f32x4* Mr = (const f32x4*)&Ml[mi][0];
        f32x4 Mreg[16];
        #pragma unroll
        for (int l = 0; l < 16; ++l) Mreg[l] = Mr[l];
        float P[8], res[8];
        #pragma unroll
        for (int c = 0; c < 8; ++c) { const float iv = (c == r8) ? 1.f : 0.f; P[c] = iv; res[c] = iv; }
        #pragma unroll
        for (int n = 1; n <= 6; ++n) {
            float tmp[8] = {0.f,0.f,0.f,0.f,0.f,0.f,0.f,0.f};
            const float invn = 1.f / (float)n;
            #pragma unroll
            for (int l = 0; l < 8; ++l) {
                const f32x4 m0 = Mreg[l * 2], m1 = Mreg[l * 2 + 1];
                const float pl = P[l];
                #pragma unroll
                for (int c = 0; c < 4; ++c) {
                    tmp[c]     = fmaf(pl, m0[c], tmp[c]);
                    tmp[4 + c] = fmaf(pl, m1[c], tmp[4 + c]);
                }
            }
            #pragma unroll
            for (int c = 0; c < 8; ++c) { P[c] = tmp[c] * invn; res[c] += P[c]; }
        }
        const float av = aavg[((long)b * 512 + i0 + mi) * 512 + j];
        bf16x8 o;
        #pragma unroll
        for (int c = 0; c < 8; ++c) o[c] = (short)f2bf(res[c] * av);
        *(bf16x8*)(Gw + ((long)(b * 8 + r8) * 512 + (i0 + mi)) * 4096 + (long)j * 8) = o;
    }
}

// LayerNorm over last dim (2048) -> bf16 out. One block per row.
__global__ __launch_bounds__(256)
void lnbf_k(const float* __restrict__ h, const float* __restrict__ g,
            const float* __restrict__ b, unsigned short* __restrict__ out)
{
    const long row = blockIdx.x;
    const float* r = h + row * (long)DFF;
    const int tid = threadIdx.x;
    float vals[8];
    float s = 0.f, sq = 0.f;
    #pragma unroll
    for (int e = 0; e < 8; ++e) {
        const float v = r[tid + e * 256];
        vals[e] = v; s += v; sq += v * v;
    }
    __shared__ float rs[256], rq[256];
    rs[tid] = s; rq[tid] = sq; __syncthreads();
    for (int st = 128; st > 0; st >>= 1) {
        if (tid < st) { rs[tid] += rs[tid + st]; rq[tid] += rq[tid + st]; }
        __syncthreads();
    }
    const float mean = rs[0] * (1.f / DFF);
    const float var  = rq[0] * (1.f / DFF) - mean * mean;
    const float inv  = rsqrtf(var + 1e-5f);
    unsigned short* o = out + row * (long)DFF;
    #pragma unroll
    for (int e = 0; e < 8; ++e) {
        const int c = tid + e * 256;
        o[c] = f2bf((vals[e] - mean) * inv * g[c] + b[c]);
    }
}

// Softmax over last dim (512), in-place fp32 + bf16 copy.
__global__ __launch_bounds__(256)
void softmax_k(float* __restrict__ p, unsigned short* __restrict__ pb)
{
    const long row = blockIdx.x;
    float* r = p + row * 512;
    const int tid = threadIdx.x;
    float v0 = r[tid], v1 = r[tid + 256];
    __shared__ float red[256];
    red[tid] = fmaxf(v0, v1); __syncthreads();
    for (int s = 128; s > 0; s >>= 1) {
        if (tid < s) red[tid] = fmaxf(red[tid], red[tid + s]);
        __syncthreads();
    }
    const float m = red[0]; __syncthreads();
    v0 = expf(v0 - m); v1 = expf(v1 - m);
    red[tid] = v0 + v1; __syncthreads();
    for (int s = 128; s > 0; s >>= 1) {
        if (tid < s) red[tid] += red[tid + s];
        __syncthreads();
    }
    const float inv = 1.f / red[0];
    const float a0 = v0 * inv, a1 = v1 * inv;
    r[tid] = a0; r[tid + 256] = a1;
    unsigned short* rb = pb + row * 512;
    rb[tid] = f2bf(a0); rb[tid + 256] = f2bf(a1);
}

__global__ __launch_bounds__(256)
void aavg_k(const float* __restrict__ attn, float* __restrict__ aavg)
{
    const long idx = (long)blockIdx.x * 256 + threadIdx.x;
    const int b = (int)(idx >> 18);
    const long rem = idx & 262143;
    float s = 0.f;
    #pragma unroll
    for (int h = 0; h < HH; ++h)
        s += attn[(long)b * 2097152 + (long)h * 262144 + rem];
    aavg[idx] = s * 0.125f;
}

// [R][C] fp32 -> [C][R] bf16 transpose
__global__ __launch_bounds__(256)
void tconv_k(const float* __restrict__ in, unsigned short* __restrict__ out,
             int R, int C)
{
    __shared__ float Ls[64][65];
    const int c0 = blockIdx.x * 64, r0 = blockIdx.y * 64;
    const int tid = threadIdx.x;
    const int tc = tid & 63, tr = tid >> 6;
    #pragma unroll
    for (int p = 0; p < 16; ++p)
        Ls[tr + p * 4][tc] = in[(long)(r0 + tr + p * 4) * C + c0 + tc];
    __syncthreads();
    #pragma unroll
    for (int p = 0; p < 16; ++p)
        out[(long)(c0 + tr + p * 4) * R + r0 + tc] = f2bf(Ls[tc][tr + p * 4]);
}

// four 512x512 fp32 -> bf16 transposes in one launch (z selects matrix);
// outputs contiguous at outbase + z*262144 (Wqt,Wkt,Wvt,Wot layout).
__global__ __launch_bounds__(256)
void tconv4_k(const float* __restrict__ W0, const float* __restrict__ W1,
              const float* __restrict__ W2, const float* __restrict__ W3,
              unsigned short* __restrict__ outbase)
{
    __shared__ float Ls[64][65];
    const int z = blockIdx.z;
    const float* in = (z == 0) ? W0 : (z == 1) ? W1 : (z == 2) ? W2 : W3;
    unsigned short* out = outbase + (long)z * 262144;
    const int c0 = blockIdx.x * 64, r0 = blockIdx.y * 64;
    const int tid = threadIdx.x;
    const int tc = tid & 63, tr = tid >> 6;
    #pragma unroll
    for (int p = 0; p < 16; ++p)
        Ls[tr + p * 4][tc] = in[(long)(r0 + tr + p * 4) * 512 + c0 + tc];
    __syncthreads();
    #pragma unroll
    for (int p = 0; p < 16; ++p)
        out[(long)(c0 + tr + p * 4) * 512 + r0 + tc] = f2bf(Ls[tc][tr + p * 4]);
}

// Wc2 [2048][32768] fp32 -> Wc2p [32768][2048] bf16: out[kl*512+d][f] = in[f][d*64+kl]
__global__ __launch_bounds__(256)
void wc2p_k(const float* __restrict__ in, unsigned short* __restrict__ out)
{
    __shared__ float Ls[64][65];
    const int d0 = blockIdx.x;
    const long f0 = blockIdx.y * 64;
    const int tid = threadIdx.x;
    const int tc = tid & 63, tr = tid >> 6;
    #pragma unroll
    for (int p = 0; p < 16; ++p)
        Ls[tr + p * 4][tc] = in[(f0 + tr + p * 4) * 32768 + (long)d0 * 64 + tc];
    __syncthreads();
    #pragma unroll
    for (int p = 0; p < 16; ++p) {
        const int kl = tr + p * 4;
        out[((long)kl * 512 + d0) * 2048 + f0 + tc] = f2bf(Ls[tc][kl]);
    }
}

__global__ __launch_bounds__(256)
void f2bf_k(const float* __restrict__ in, unsigned short* __restrict__ out, int n)
{
    const int i = blockIdx.x * 256 + threadIdx.x;
    if (i < n) out[i] = f2bf(in[i]);
}

extern "C" void kernel_launch(void* const* d_in, const int* in_sizes, int n_in,
                              void* d_out, int out_size, void* d_ws, size_t ws_size,
                              hipStream_t stream) {
    const float* x   = (const float*)d_in[0];
    const float* u   = (const float*)d_in[1];
    const float* Wq  = (const float*)d_in[2];  const float* bq  = (const float*)d_in[3];
    const float* Wk  = (const float*)d_in[4];  const float* bk  = (const float*)d_in[5];
    const float* Wv  = (const float*)d_in[6];  const float* bv  = (const float*)d_in[7];
    const float* Wo  = (const float*)d_in[8];  const float* bo  = (const float*)d_in[9];
    const float* Wfp = (const float*)d_in[10]; const float* bfp = (const float*)d_in[11];
    const float* Wfo = (const float*)d_in[12]; const float* bfo = (const float*)d_in[13];
    const float* Wc1 = (const float*)d_in[14]; const float* bc1 = (const float*)d_in[15];
    const float* gln = (const float*)d_in[16]; const float* bln = (const float*)d_in[17];
    const float* Wc2 = (const float*)d_in[18]; const float* bc2 = (const float*)d_in[19];

    float* ws = (float*)d_ws;
    // float-unit offsets; Gw aliases Wc2p (dead after fc2). Peak ~313 MB.
    unsigned short* Wc2p = (unsigned short*)(ws);                     // 33,554,432 fu
    unsigned short* Gw   = (unsigned short*)(ws);                     // alias
    unsigned short* At   = (unsigned short*)(ws + 33554432);          // 16,777,216 fu
    float*          h    = ws + 50331648;                             //  2,097,152 fu
    unsigned short* h_bf = (unsigned short*)(ws + 52428800);          //  1,048,576 fu
    unsigned short* x_bf = (unsigned short*)(ws + 53477376);          //    262,144 fu
    unsigned short* u_bf = (unsigned short*)(ws + 53739520);          //     32,768 fu
    unsigned short* Wc1t = (unsigned short*)(ws + 53772288);          //    524,288 fu
    unsigned short* Wqt  = (unsigned short*)(ws + 54296576);          //    131,072 fu
    unsigned short* Wkt  = (unsigned short*)(ws + 54427648);          // (contiguous
    unsigned short* Wvt  = (unsigned short*)(ws + 54558720);          //  after Wqt)
    unsigned short* Wot  = (unsigned short*)(ws + 54689792);
    unsigned short* Wfpt = (unsigned short*)(ws + 54820864);          //     16,384 fu
    unsigned short* Wfot = (unsigned short*)(ws + 54837248);          //     16,384 fu
    float*          xa   = ws + 54853632;                             // (unused now)
    unsigned short* q_bf = (unsigned short*)(ws + 54919168);          //    262,144 fu
    unsigned short* k_bf = (unsigned short*)(ws + 55181312);
    unsigned short* vT   = (unsigned short*)(ws + 55443456);
    float*          sc   = ws + 55705600;                             //  4,194,304 fu
    unsigned short* at_bf= (unsigned short*)(ws + 59899904);          //  2,097,152 fu
    float*          av   = ws + 61997056;                             //    524,288 fu
    unsigned short* ctx  = (unsigned short*)(ws + 62521344);          //    262,144 fu
    unsigned short* upT2 = (unsigned short*)(ws + 62783488);
    unsigned short* ut_bf= (unsigned short*)(ws + 63045632);
    // split-K fp32 partial buffers (beyond old 253 MB peak; ws is 1 GiB)
    float*          qkvp = ws + 63307776;                             //  6,291,456 fu
    float*          wop  = ws + 69599232;                             //  2,097,152 fu
    float*          ctxp = ws + 71696384;
    float*          utp  = ws + 73793536;                             //  4,194,304 fu
    float*          up   = ws + 77987840;                             //    262,144 fu
    float* xout = (float*)d_out;
    float* uout = xout + 524288;
    (void)xa;

    const dim3 blk(256);

    // fc2_k needs 160 KiB dynamic LDS: opt in (host-side, graph-capture safe)
    hipFuncSetAttribute(reinterpret_cast<const void*>(fc2_k),
                        hipFuncAttributeMaxDynamicSharedMemorySize, 163840);

    // --- conversions ---
    tconv_k<<<dim3(32, 8), blk, 0, stream>>>(Wc1, Wc1t, 512, 2048);
    tconv4_k<<<dim3(8, 8, 4), blk, 0, stream>>>(Wq, Wk, Wv, Wo, Wqt);
    tconv_k<<<dim3(8, 1), blk, 0, stream>>>(Wfp, Wfpt, 64, 512);
    tconv_k<<<dim3(1, 8), blk, 0, stream>>>(Wfo, Wfot, 512, 64);
    wc2p_k<<<dim3(512, 32), blk, 0, stream>>>(Wc2, Wc2p);
    f2bf_k<<<dim3(2048), blk, 0, stream>>>(x, x_bf, 524288);
    f2bf_k<<<dim3(256), blk, 0, stream>>>(u, u_bf, 65536);

    // --- attention: fused QKV projection (N=1536, split-K x4) + fused reduce ---
    mgemm_k<128,7,4><<<dim3(48, 8, 1), blk, 0, stream>>>(
        x_bf, Wqt, nullptr, nullptr, qkvp, nullptr, 512, 512, 512, 1536,
        1, 0,0,0,0, 0,1572864, 1.0f);
    redqkv_k<<<dim3(6, 1024), blk, 0, stream>>>(qkvp, bq, bk, bv, q_bf, k_bf, vT);
    // scores = q.k^T/8, batched (b,h)
    mgemm_k<128,0><<<dim3(4, 4, 16), blk, 0, stream>>>(
        q_bf, k_bf, nullptr, nullptr, sc, nullptr, 64, 512, 512, 512,
        8, 262144,64, 262144,64, 2097152,262144, 0.125f);
    softmax_k<<<dim3(BB * HH * SS), blk, 0, stream>>>(sc, at_bf);
    aavg_k<<<dim3(2048), blk, 0, stream>>>(sc, av);
    // ctx = attn @ v, batched (b,h), split-K x4
    mgemm_k<64,7,4><<<dim3(4, 4, 16), blk, 0, stream>>>(
        at_bf, vT, nullptr, nullptr, ctxp, nullptr, 512, 512, 512, 64,
        8, 2097152,262144, 262144,32768, 32768,524288, 1.0f);
    redzc_k<4><<<dim3(2048), blk, 0, stream>>>(ctxp, ctx);
    // x_out = x + ctx @ Wo + bo, split-K x4
    mgemm_k<128,7,4><<<dim3(16, 8, 1), blk, 0, stream>>>(
        ctx, Wot, nullptr, nullptr, wop, nullptr, 512, 512, 512, 512,
        1, 0,0,0,0, 0,524288, 1.0f);
    redwo_k<<<dim3(2048), blk, 0, stream>>>(wop, bo, x, xout);

    // --- connection network ---
    mgemm_k<128,1><<<dim3(16, 8, 1), blk, 0, stream>>>(
        x_bf, Wc1t, bc1, nullptr, h, nullptr, 512, 512, 512, 2048,
        1, 0,0,0,0,0,0, 1.0f);
    lnbf_k<<<dim3(1024), blk, 0, stream>>>(h, gln, bln, h_bf);
    // fc2: 256x256-tile 8-wave pipelined GEMM, B triple-buffered (2 tiles deep)
    fc2_k<<<dim3(512), dim3(512), 163840, stream>>>(h_bf, Wc2p, bc2, At);
    // liegamma now computes xa in-kernel (xa_k eliminated)
    liegamma_k<<<dim3(4, 512, 2), blk, 0, stream>>>(x_bf, At, x, av, Gw);

    // --- fiber transport ---
    mgemm_k<128,6><<<dim3(4, 8, 1), blk, 0, stream>>>(
        u_bf, Wfpt, bfp, nullptr, nullptr, upT2, 64, 64, 64, 512,
        1, 0,0,0,0,0,0, 1.0f);
    // ut[b,i,k*64+c] = Gw[b,k] @ upT2[b]^T, batched (b,k), split-K x8
    mgemm_k<64,7,8><<<dim3(8, 4, 16), blk, 0, stream>>>(
        Gw, upT2, nullptr, nullptr, utp, nullptr, 4096, 4096, 4096, 64,
        8, 16777216,2097152, 262144,0, 32768,524288, 1.0f);
    redzc_k<8><<<dim3(2048), blk, 0, stream>>>(utp, ut_bf);
    // u_out = u + ut @ Wfo + bfo, split-K x4
    mgemm_k<64,7,4><<<dim3(4, 8, 1), blk, 0, stream>>>(
        ut_bf, Wfot, nullptr, nullptr, up, nullptr, 512, 512, 512, 64,
        1, 0,0,0,0, 0,65536, 1.0f);
    redu_k<<<dim3(256), blk, 0, stream>>>(up, bfo, u, uout);
}

// Round 9
// 814.100 us; speedup vs baseline: 1.1597x; 1.0109x over previous
//
#include <hip/hip_runtime.h>
#include <math.h>

// B,S,D,K,DF,H,DFF = 2,512,512,8,64,8,2048
#define BB 2
#define SS 512
#define DD 512
#define HH 8
#define DFF 2048

typedef __attribute__((ext_vector_type(8))) short bf16x8;
typedef __attribute__((ext_vector_type(4))) float f32x4;

__device__ __forceinline__ float gelu_exact(float v) {
    return 0.5f * v * (1.0f + erff(v * 0.70710678118654752f));
}
__device__ __forceinline__ unsigned short f2bf(float f) {
    unsigned u = __float_as_uint(f);
    u += 0x7FFF + ((u >> 16) & 1);
    return (unsigned short)(u >> 16);
}
__device__ __forceinline__ float bf2f(unsigned short s) {
    return __uint_as_float(((unsigned)s) << 16);
}
__device__ __forceinline__ void gload16(const void* g, void* l) {
    __builtin_amdgcn_global_load_lds((const __attribute__((address_space(1))) void*)g,
                                     (__attribute__((address_space(3))) void*)l, 16, 0, 0);
}

// ---------------- flexible bf16 MFMA GEMM: C = epi(A @ B^T) ----------------
// A [M,K] bf16 (lda), B [N,K] bf16 (ldb, i.e. B^T layout). 128xNT tile, BK=32,
// 256 threads (4 waves 2x2), 16x16x32 MFMA. Batched over blockIdx.z.
// EPI: 0 fp32 out (scale, no bias) | 1 fp32 bias+gelu | 2 bf16 perm-bias (fc2)
//      3 bf16 out (+opt bias)      | 4 fp32 bias+resid | 5 bf16 vT-store
//      6 bf16 upT2-store           | 7 fp32 split-K partial (no bias):
//         Cf[z*cSB + chunk*cSH + row*ldc + col], chunk = blockIdx.x % SK.
template<int NT, int EPI, int SK = 1>
__global__ __launch_bounds__(256)
void mgemm_k(const unsigned short* __restrict__ A, const unsigned short* __restrict__ B,
             const float* __restrict__ bias, const float* __restrict__ resid,
             float* __restrict__ Cf, unsigned short* __restrict__ Cb,
             int K, int lda, int ldb, int ldc, int batchH,
             long aSB, long aSH, long bSB, long bSH, long cSB, long cSH,
             float scale)
{
    __shared__ unsigned short As[128][32];
    __shared__ unsigned short Bs[NT][32];
    const int tid = threadIdx.x;
    const int wave = tid >> 6, lane = tid & 63;
    const int z = blockIdx.z;
    const int zb = z / batchH, zh = z % batchH;
    const unsigned short* Ab = A + (long)zb * aSB + (long)zh * aSH;
    const unsigned short* Bb = B + (long)zb * bSB + (long)zh * bSH;
    const int chunk = (SK > 1) ? ((int)blockIdx.x % SK) : 0;
    const int colb  = (SK > 1) ? ((int)blockIdx.x / SK) : (int)blockIdx.x;
    const int row0 = blockIdx.y * 128, col0 = colb * NT;
    const int wm = wave >> 1, wn = wave & 1;
    const int lm = lane & 15, quad = lane >> 4;
    const int lrow = lane >> 2, lk = (lane & 3) * 8;
    constexpr int NTW = NT / 32;     // n-subtiles per wave
    f32x4 acc[4][NTW];
    #pragma unroll
    for (int i = 0; i < 4; ++i)
        #pragma unroll
        for (int j = 0; j < NTW; ++j) acc[i][j] = (f32x4)0.f;

    const int kLo = chunk * (K / SK), kHi = kLo + K / SK;
    for (int k0 = kLo; k0 < kHi; k0 += 32) {
        #pragma unroll
        for (int t = 0; t < 2; ++t) {
            const int r = wave * 32 + t * 16;
            gload16(Ab + (long)(row0 + r + lrow) * lda + k0 + lk, &As[r][0]);
        }
        if (NT == 128) {
            #pragma unroll
            for (int t = 0; t < 2; ++t) {
                const int r = wave * 32 + t * 16;
                gload16(Bb + (long)(col0 + r + lrow) * ldb + k0 + lk, &Bs[r][0]);
            }
        } else {
            const int r = wave * 16;
            gload16(Bb + (long)(col0 + r + lrow) * ldb + k0 + lk, &Bs[r][0]);
        }
        __syncthreads();
        bf16x8 af[4], bfr[NTW];
        #pragma unroll
        for (int mt = 0; mt < 4; ++mt)
            af[mt] = *(const bf16x8*)&As[wm * 64 + mt * 16 + lm][quad * 8];
        #pragma unroll
        for (int nt = 0; nt < NTW; ++nt)
            bfr[nt] = *(const bf16x8*)&Bs[wn * (NT / 2) + nt * 16 + lm][quad * 8];
        #pragma unroll
        for (int mt = 0; mt < 4; ++mt)
            #pragma unroll
            for (int nt = 0; nt < NTW; ++nt)
                acc[mt][nt] = __builtin_amdgcn_mfma_f32_16x16x32_bf16(
                    af[mt], bfr[nt], acc[mt][nt], 0, 0, 0);
        __syncthreads();
    }
    float* Cfz = (Cf && EPI != 7) ? Cf + (long)zb * cSB + (long)zh * cSH : Cf;
    unsigned short* Cbz = Cb ? Cb + (long)zb * cSB + (long)zh * cSH : nullptr;
    #pragma unroll
    for (int mt = 0; mt < 4; ++mt) {
        #pragma unroll
        for (int nt = 0; nt < NTW; ++nt) {
            #pragma unroll
            for (int r = 0; r < 4; ++r) {
                const int row = row0 + wm * 64 + mt * 16 + quad * 4 + r;
                const int col = col0 + wn * (NT / 2) + nt * 16 + lm;
                float v = acc[mt][nt][r] * scale;
                if (EPI == 2)      v += bias[(col & 511) * 64 + (col >> 9)];
                else if (EPI == 1 || EPI == 4) v += bias[col];
                else if ((EPI == 3 || EPI == 5 || EPI == 6) && bias) v += bias[col];
                if (EPI == 1) v = gelu_exact(v);
                if (EPI == 4) v += resid[(long)row * ldc + col];
                if (EPI == 0 || EPI == 1 || EPI == 4)
                    Cfz[(long)row * ldc + col] = v;
                else if (EPI == 7)  // split-K fp32 partial
                    Cf[(long)z * cSB + (long)chunk * cSH + (long)row * ldc + col] = v;
                else if (EPI == 2 || EPI == 3)
                    Cbz[(long)row * ldc + col] = f2bf(v);
                else if (EPI == 5)  // vT[b][h][c][j]: rows=(b,j), col=h*64+c
                    Cb[(long)(row >> 9) * 262144 + (col >> 6) * 32768 +
                       (col & 63) * 512 + (row & 511)] = f2bf(v);
                else if (EPI == 6)  // upT2[b][c][j*8+l]: rows=(b,j), col=l*64+c
                    Cb[(long)(row >> 9) * 262144 + (col & 63) * 4096 +
                       (row & 511) * 8 + (col >> 6)] = f2bf(v);
            }
        }
    }
}

// ---- split-K reduce kernels (fold EPI semantics over SK partials) ----
// fused QKV reduce: p[4][1024][1536]; col segment 0=q,1=k,2=v. grid (6,1024).
__global__ __launch_bounds__(256)
void redqkv_k(const float* __restrict__ p, const float* __restrict__ bq,
              const float* __restrict__ bk, const float* __restrict__ bv,
              unsigned short* __restrict__ q_bf, unsigned short* __restrict__ k_bf,
              unsigned short* __restrict__ vT)
{
    const int col = blockIdx.x * 256 + threadIdx.x;   // [0,1536)
    const int row = blockIdx.y;                        // [0,1024)
    const long base = (long)row * 1536 + col;
    float s = p[base] + p[base + 1572864] + p[base + 3145728] + p[base + 4718592];
    const int which = col >> 9;       // uniform per block (256 | 512)
    const int scol = col & 511;
    if (which == 0) {
        q_bf[(long)row * 512 + scol] = f2bf(s + bq[scol]);
    } else if (which == 1) {
        k_bf[(long)row * 512 + scol] = f2bf(s + bk[scol]);
    } else {
        s += bv[scol];
        vT[(long)(row >> 9) * 262144 + (scol >> 6) * 32768 +
           (scol & 63) * 512 + (row & 511)] = f2bf(s);
    }
}
// Wo: xout = x + bo + Sigma (EPI=4 semantics, fp32)
__global__ __launch_bounds__(256)
void redwo_k(const float* __restrict__ p, const float* __restrict__ bias,
             const float* __restrict__ resid, float* __restrict__ out)
{
    const long idx = (long)blockIdx.x * 256 + threadIdx.x;  // 524288
    out[idx] = resid[idx] + bias[idx & 511]
             + p[idx] + p[idx + 524288] + p[idx + 1048576] + p[idx + 1572864];
}
// ctx/ut: partial layout p[chunk][z=(b,zh)][i][c] -> out bf16 [b][i][zh*64+c]
template<int SK>
__global__ __launch_bounds__(256)
void redzc_k(const float* __restrict__ p, unsigned short* __restrict__ out)
{
    const long idx = (long)blockIdx.x * 256 + threadIdx.x;  // z*32768+i*64+c
    float s = 0.f;
    #pragma unroll
    for (int k = 0; k < SK; ++k) s += p[idx + (long)k * 524288];
    const int b = (int)(idx >> 18), zh = (int)((idx >> 15) & 7);
    const long rem = idx & 32767;
    const int i = (int)(rem >> 6), c = (int)(rem & 63);
    out[(long)b * 262144 + (long)i * 512 + zh * 64 + c] = f2bf(s);
}
// uout = u + bfo + Sigma (fp32, 65536 elems, chunk stride 65536)
__global__ __launch_bounds__(256)
void redu_k(const float* __restrict__ p, const float* __restrict__ bias,
            const float* __restrict__ resid, float* __restrict__ out)
{
    const long idx = (long)blockIdx.x * 256 + threadIdx.x;  // 65536
    out[idx] = resid[idx] + bias[idx & 63]
             + p[idx] + p[idx + 65536] + p[idx + 131072] + p[idx + 196608];
}

// ---------- fused attention: S = q.k^T/8, row softmax, bf16 store ----------
// Grid (8, 16) = (i-block of 64 rows, z=(b*8+h)), 512 threads = 8 waves.
// Stage q[64][64] + k[512][64] in LDS (fc2-style wave-uniform gload16 dest +
// chunk16 XOR swizzle); wave w computes S[64][64] for cols w*64..w*64+63;
// row softmax via shfl-xor(1,2,4,8) within 16-lane groups + 8-wave LDS fold.
// Writes at[z][i][j] bf16 only (sc fp32 buffer eliminated).
__global__ __launch_bounds__(512)
void attn_k(const unsigned short* __restrict__ q_bf, const unsigned short* __restrict__ k_bf,
            unsigned short* __restrict__ at)
{
    extern __shared__ unsigned short sm[];
    unsigned short* Qs = sm;                  // 4096 shorts  ([64][64] swz)
    unsigned short* Ks = sm + 4096;           // 32768 shorts ([512][64] swz)
    float* redm = (float*)(sm + 36864);       // [64][8]
    float* rowv = redm + 512;                 // [64]
    const int tid = threadIdx.x;
    const int wave = tid >> 6, lane = tid & 63;
    const int lm = lane & 15, quad = lane >> 4;
    const int z = blockIdx.y, h = z & 7, b = z >> 3;
    const int i0 = blockIdx.x * 64;
    const unsigned short* Qg = q_bf + (long)b * 262144;
    const unsigned short* Kg = k_bf + (long)b * 262144;
    // staging: lane covers 16B chunk (lane&7) of local row wave*8+(lane>>3)
    const int srow = wave * 8 + (lane >> 3);
    const int scx = ((lane & 7) ^ ((lane >> 3) & 7)) * 8;   // pre-swizzled src chunk
    gload16(Qg + (long)(i0 + srow) * 512 + h * 64 + scx, Qs + wave * 512);
    #pragma unroll
    for (int p = 0; p < 8; ++p)
        gload16(Kg + (long)(p * 64 + srow) * 512 + h * 64 + scx,
                Ks + p * 4096 + wave * 512);
    asm volatile("s_waitcnt vmcnt(0)" ::: "memory");
    __syncthreads();

    const int axor = lm & 7;
    const int ca0 = ((quad) ^ axor) * 8;
    const int ca1 = ((quad + 4) ^ axor) * 8;
    bf16x8 af[4][2], bfk[4][2];
    #pragma unroll
    for (int mt = 0; mt < 4; ++mt) {
        af[mt][0] = *(const bf16x8*)&Qs[(mt * 16 + lm) * 64 + ca0];
        af[mt][1] = *(const bf16x8*)&Qs[(mt * 16 + lm) * 64 + ca1];
    }
    #pragma unroll
    for (int nt = 0; nt < 4; ++nt) {
        bfk[nt][0] = *(const bf16x8*)&Ks[(wave * 64 + nt * 16 + lm) * 64 + ca0];
        bfk[nt][1] = *(const bf16x8*)&Ks[(wave * 64 + nt * 16 + lm) * 64 + ca1];
    }
    f32x4 acc[4][4];
    #pragma unroll
    for (int i = 0; i < 4; ++i)
        #pragma unroll
        for (int j = 0; j < 4; ++j) acc[i][j] = (f32x4)0.f;
    #pragma unroll
    for (int mt = 0; mt < 4; ++mt)
        #pragma unroll
        for (int nt = 0; nt < 4; ++nt) {
            acc[mt][nt] = __builtin_amdgcn_mfma_f32_16x16x32_bf16(
                af[mt][0], bfk[nt][0], acc[mt][nt], 0, 0, 0);
            acc[mt][nt] = __builtin_amdgcn_mfma_f32_16x16x32_bf16(
                af[mt][1], bfk[nt][1], acc[mt][nt], 0, 0, 0);
        }
    #pragma unroll
    for (int mt = 0; mt < 4; ++mt)
        #pragma unroll
        for (int nt = 0; nt < 4; ++nt)
            #pragma unroll
            for (int r = 0; r < 4; ++r) acc[mt][nt][r] *= 0.125f;
    // per-wave row max (over its 64 cols)
    #pragma unroll
    for (int mt = 0; mt < 4; ++mt)
        #pragma unroll
        for (int r = 0; r < 4; ++r) {
            float m = fmaxf(fmaxf(acc[mt][0][r], acc[mt][1][r]),
                            fmaxf(acc[mt][2][r], acc[mt][3][r]));
            m = fmaxf(m, __shfl_xor(m, 1));
            m = fmaxf(m, __shfl_xor(m, 2));
            m = fmaxf(m, __shfl_xor(m, 4));
            m = fmaxf(m, __shfl_xor(m, 8));
            if (lm == 0) redm[(mt * 16 + quad * 4 + r) * 8 + wave] = m;
        }
    __syncthreads();
    if (tid < 64) {
        float m = redm[tid * 8];
        #pragma unroll
        for (int w = 1; w < 8; ++w) m = fmaxf(m, redm[tid * 8 + w]);
        rowv[tid] = m;
    }
    __syncthreads();
    // exp + per-wave row sum
    #pragma unroll
    for (int mt = 0; mt < 4; ++mt)
        #pragma unroll
        for (int r = 0; r < 4; ++r) {
            const float rm = rowv[mt * 16 + quad * 4 + r];
            float s = 0.f;
            #pragma unroll
            for (int nt = 0; nt < 4; ++nt) {
                const float e = expf(acc[mt][nt][r] - rm);
                acc[mt][nt][r] = e; s += e;
            }
            s += __shfl_xor(s, 1);
            s += __shfl_xor(s, 2);
            s += __shfl_xor(s, 4);
            s += __shfl_xor(s, 8);
            if (lm == 0) redm[(mt * 16 + quad * 4 + r) * 8 + wave] = s;
        }
    __syncthreads();
    if (tid < 64) {
        float s = redm[tid * 8];
        #pragma unroll
        for (int w = 1; w < 8; ++w) s += redm[tid * 8 + w];
        rowv[tid] = 1.f / s;
    }
    __syncthreads();
    unsigned short* ao = at + (long)z * 262144;
    #pragma unroll
    for (int mt = 0; mt < 4; ++mt)
        #pragma unroll
        for (int r = 0; r < 4; ++r) {
            const int row = mt * 16 + quad * 4 + r;
            const float inv = rowv[row];
            #pragma unroll
            for (int nt = 0; nt < 4; ++nt)
                ao[(long)(i0 + row) * 512 + wave * 64 + nt * 16 + lm] =
                    f2bf(acc[mt][nt][r] * inv);
        }
}

// aavg from bf16 attn: av[b,i,j] = mean_h at[b,h,i,j]. 4 j's/thread, grid 512.
__global__ __launch_bounds__(256)
void aavg_k(const unsigned short* __restrict__ at, float* __restrict__ av)
{
    const long idx4 = ((long)blockIdx.x * 256 + threadIdx.x) * 4;  // over 524288
    const int b = (int)(idx4 >> 18);
    const long rem = idx4 & 262143;
    float s0 = 0.f, s1 = 0.f, s2 = 0.f, s3 = 0.f;
    #pragma unroll
    for (int h = 0; h < HH; ++h) {
        const unsigned long long w = *(const unsigned long long*)
            &at[(long)b * 2097152 + (long)h * 262144 + rem];
        s0 += bf2f((unsigned short)(w));
        s1 += bf2f((unsigned short)(w >> 16));
        s2 += bf2f((unsigned short)(w >> 32));
        s3 += bf2f((unsigned short)(w >> 48));
    }
    f32x4 o; o[0] = s0 * 0.125f; o[1] = s1 * 0.125f; o[2] = s2 * 0.125f; o[3] = s3 * 0.125f;
    *(f32x4*)&av[idx4] = o;
}

// ---------- fc2: 256x256-tile 8-wave 4-phase pipelined GEMM (T2+T3+T4+T5) ----------
// (A dbuf + B triple-buffered, 160 KiB LDS, counted vmcnt(8)/vmcnt(6))
__global__ __launch_bounds__(512, 2)
void fc2_k(const unsigned short* __restrict__ A, const unsigned short* __restrict__ Bm,
           const float* __restrict__ bias, unsigned short* __restrict__ C)
{
    extern __shared__ unsigned short smraw[];   // 81920 shorts = 160 KiB
#define SMA(ab, h) (smraw + (((ab) * 2 + (h)) * 8192))
#define SMB(bb, h) (smraw + (32768 + ((bb) * 2 + (h)) * 8192))
    const int tid = threadIdx.x;
    const int wave = tid >> 6, lane = tid & 63;
    const int bid = blockIdx.x;
    const int lin = (bid & 7) * 64 + (bid >> 3);
    const int by = lin & 3, bx = lin >> 2;
    const int row0 = by * 256, col0 = bx * 256;
    const int wm = wave >> 2, wn = wave & 3;          // 2 x 4 wave grid
    const int lm = lane & 15, quad = lane >> 4;
    const int axor = lm & 7;
    const int arow = (wm * 64 + lm) * 64;
    const int brow = (wn * 32 + lm) * 64;
    const int ca0 = ((quad) ^ axor) * 8;              // kk=0 chunk
    const int ca1 = ((quad + 4) ^ axor) * 8;          // kk=1 chunk
    const int srow = wave * 8 + (lane >> 3);          // local row r in [0,64)
    const int scx = ((lane & 7) ^ ((lane >> 3) & 7)) * 8;  // pre-swizzled source chunk
    const int sbrow = ((srow >> 5) << 6) + (srow & 31);    // B granule-interleave row
    const unsigned short* AgB = A + (long)(row0 + srow) * 2048 + scx;
    const unsigned short* BgB = Bm + (long)(col0 + sbrow) * 2048 + scx;

    f32x4 acc[8][4];
    #pragma unroll
    for (int i = 0; i < 8; ++i)
        #pragma unroll
        for (int j = 0; j < 4; ++j) acc[i][j] = (f32x4)0.f;
    bf16x8 afr[4][2], b0f[2][2], b1f[2][2];

#define STGA(ab, h, toff) do { \
        const unsigned short* _g = AgB + (toff) * 64 + (h) * (64 * 2048); \
        unsigned short* _d = SMA(ab, h) + wave * 512; \
        gload16(_g, _d); \
        gload16(_g + 128 * 2048, _d + 4096); \
    } while (0)
#define STGB(bb, h, toff) do { \
        const unsigned short* _g = BgB + (toff) * 64 + (h) * (32 * 2048); \
        unsigned short* _d = SMB(bb, h) + wave * 512; \
        gload16(_g, _d); \
        gload16(_g + 128 * 2048, _d + 4096); \
    } while (0)
#define RDA(Hp) do { _Pragma("unroll") for (int _m = 0; _m < 4; ++_m) { \
        afr[_m][0] = *(const bf16x8*)((Hp) + arow + _m * 1024 + ca0); \
        afr[_m][1] = *(const bf16x8*)((Hp) + arow + _m * 1024 + ca1); } } while (0)
#define RDB(bf, Hp) do { _Pragma("unroll") for (int _n = 0; _n < 2; ++_n) { \
        bf[_n][0] = *(const bf16x8*)((Hp) + brow + _n * 1024 + ca0); \
        bf[_n][1] = *(const bf16x8*)((Hp) + brow + _n * 1024 + ca1); } } while (0)
#define MM(QM, QN, bf) do { _Pragma("unroll") for (int _m = 0; _m < 4; ++_m) \
        _Pragma("unroll") for (int _n = 0; _n < 2; ++_n) { \
        acc[(QM)*4+_m][(QN)*2+_n] = __builtin_amdgcn_mfma_f32_16x16x32_bf16( \
            afr[_m][0], bf[_n][0], acc[(QM)*4+_m][(QN)*2+_n], 0, 0, 0); \
        acc[(QM)*4+_m][(QN)*2+_n] = __builtin_amdgcn_mfma_f32_16x16x32_bf16( \
            afr[_m][1], bf[_n][1], acc[(QM)*4+_m][(QN)*2+_n], 0, 0, 0); } } while (0)
#define PH_MID() \
        __builtin_amdgcn_s_barrier(); \
        asm volatile("s_waitcnt lgkmcnt(0)" ::: "memory"); \
        __builtin_amdgcn_sched_barrier(0); \
        __builtin_amdgcn_s_setprio(1)
#define PH_END(VM) \
        __builtin_amdgcn_s_setprio(0); \
        __builtin_amdgcn_sched_barrier(0); \
        asm volatile("s_waitcnt vmcnt(" #VM ")" ::: "memory"); \
        __builtin_amdgcn_sched_barrier(0); \
        __builtin_amdgcn_s_barrier()
#define PH_END_NW() \
        __builtin_amdgcn_s_setprio(0); \
        __builtin_amdgcn_sched_barrier(0); \
        __builtin_amdgcn_s_barrier()

    STGB(0, 0, 0);
    STGB(0, 1, 0);
    STGA(0, 0, 0);
    STGA(0, 1, 0);
    STGB(1, 0, 1);
    STGB(1, 1, 1);
    asm volatile("s_waitcnt vmcnt(6)" ::: "memory");
    __builtin_amdgcn_s_barrier();

    int rA = 0;
    int rB = 0, mB = 1, wB = 2;
    #pragma unroll 1
    for (int t = 0; t < 32; ++t) {
        const int tA = (t + 1 < 32) ? (t + 1) : 31;
        const int tB = (t + 2 < 32) ? (t + 2) : 31;
        const unsigned short* A0p = SMA(rA, 0);
        const unsigned short* A1p = SMA(rA, 1);
        const unsigned short* B0p = SMB(rB, 0);
        const unsigned short* B1p = SMB(rB, 1);
        RDA(A0p); RDB(b0f, B0p);
        STGA(rA ^ 1, 0, tA);
        PH_MID(); MM(0, 0, b0f); PH_END_NW();
        RDB(b1f, B1p);
        STGA(rA ^ 1, 1, tA);
        PH_MID(); MM(0, 1, b1f); PH_END(8);
        RDA(A1p);
        STGB(wB, 0, tB);
        PH_MID(); MM(1, 1, b1f); PH_END_NW();
        STGB(wB, 1, tB);
        PH_MID(); MM(1, 0, b0f); PH_END(6);
        rA ^= 1;
        const int tmp = rB; rB = mB; mB = wB; wB = tmp;
    }
    asm volatile("s_waitcnt vmcnt(0)" ::: "memory");

    const int crow = row0 + wm * 128 + quad * 4;
    const int ccol0 = col0 + wn * 64 + lm;
    #pragma unroll
    for (int ms = 0; ms < 8; ++ms)
        #pragma unroll
        for (int ns = 0; ns < 4; ++ns) {
            const int col = ccol0 + ns * 16;
            const float bv = bias[(col & 511) * 64 + (col >> 9)];
            #pragma unroll
            for (int r = 0; r < 4; ++r) {
                const int row = crow + ms * 16 + r;
                C[(long)row * 32768 + col] = f2bf(acc[ms][ns][r] + bv);
            }
        }
#undef SMA
#undef SMB
#undef STGA
#undef STGB
#undef RDA
#undef RDB
#undef MM
#undef PH_MID
#undef PH_END
#undef PH_END_NW
}

// ------------- fused lie-GEMM + xa + 6-term Taylor matexp -> Gw (bf16) -------------
__global__ __launch_bounds__(256)
void liegamma_k(const unsigned short* __restrict__ xb, const unsigned short* __restrict__ At,
                const float* __restrict__ xf, const float* __restrict__ aavg,
                unsigned short* __restrict__ Gw)
{
    __shared__ unsigned short Xs[128][32];
    __shared__ unsigned short Ts[64][32];
    __shared__ float Ml[128][68];
    __shared__ float xjs[512];
    __shared__ float xred[64][4];
    __shared__ float xafin[64];
    const int tid = threadIdx.x;
    const int wave = tid >> 6, lane = tid & 63;
    const int b = blockIdx.z, j = blockIdx.y;
    const int i0 = blockIdx.x * 128;
    const int lm = lane & 15, quad = lane >> 4;
    const int lrow = lane >> 2, lk = (lane & 3) * 8;
    const unsigned short* Xb = xb + ((long)b * 512 + i0) * 512;
    const unsigned short* Tb = At + ((long)(b * 512 + j)) * 32768;
    const float* xrow = xf + ((long)b * 512 + j) * 512;
    xjs[tid] = xrow[tid];
    xjs[tid + 256] = xrow[tid + 256];
    f32x4 acc[2][4];
    #pragma unroll
    for (int i = 0; i < 2; ++i)
        #pragma unroll
        for (int n = 0; n < 4; ++n) acc[i][n] = (f32x4)0.f;
    float xas = 0.f;
    const int kl2 = tid >> 2, q2 = tid & 3;

    for (int k0 = 0; k0 < 512; k0 += 32) {
        #pragma unroll
        for (int t = 0; t < 2; ++t) {
            const int r = wave * 32 + t * 16;
            gload16(Xb + (long)(r + lrow) * 512 + k0 + lk, &Xs[r][0]);
        }
        {
            const int r = wave * 16;
            gload16(Tb + (long)(r + lrow) * 512 + k0 + lk, &Ts[r][0]);
        }
        __syncthreads();
        bf16x8 af[2], bfr[4];
        #pragma unroll
        for (int mt = 0; mt < 2; ++mt)
            af[mt] = *(const bf16x8*)&Xs[wave * 32 + mt * 16 + lm][quad * 8];
        #pragma unroll
        for (int nt = 0; nt < 4; ++nt)
            bfr[nt] = *(const bf16x8*)&Ts[nt * 16 + lm][quad * 8];
        #pragma unroll
        for (int mt = 0; mt < 2; ++mt)
            #pragma unroll
            for (int nt = 0; nt < 4; ++nt)
                acc[mt][nt] = __builtin_amdgcn_mfma_f32_16x16x32_bf16(
                    af[mt], bfr[nt], acc[mt][nt], 0, 0, 0);
        {
            const bf16x8 tv = *(const bf16x8*)&Ts[kl2][q2 * 8];
            const float* xs = &xjs[k0 + q2 * 8];
            #pragma unroll
            for (int e = 0; e < 8; ++e)
                xas = fmaf(xs[e], bf2f((unsigned short)tv[e]), xas);
        }
        __syncthreads();
    }
    xred[kl2][q2] = xas;
    __syncthreads();
    if (tid < 64)
        xafin[tid] = xred[tid][0] + xred[tid][1] + xred[tid][2] + xred[tid][3];
    __syncthreads();
    #pragma unroll
    for (int mt = 0; mt < 2; ++mt)
        #pragma unroll
        for (int nt = 0; nt < 4; ++nt) {
            const float xv = xafin[nt * 16 + lm];
            #pragma unroll
            for (int r = 0; r < 4; ++r)
                Ml[wave * 32 + mt * 16 + quad * 4 + r][nt * 16 + lm] = xv - acc[mt][nt][r];
        }
    __syncthreads();
    const int r8 = tid & 7, mg = tid >> 3;
    #pragma unroll 1
    for (int pass = 0; pass < 4; ++pass) {
        const int mi = pass * 32 + mg;
        const f32x4* Mr = (const f32x4*)&Ml[mi][0];
        f32x4 Mreg[16];
        #pragma unroll
        for (int l = 0; l < 16; ++l) Mreg[l] = Mr[l];
        float P[8], res[8];
        #pragma unroll
        for (int c = 0; c < 8; ++c) { const float iv = (c == r8) ? 1.f : 0.f; P[c] = iv; res[c] = iv; }
        #pragma unroll
        for (int n = 1; n <= 6; ++n) {
            float tmp[8] = {0.f,0.f,0.f,0.f,0.f,0.f,0.f,0.f};
            const float invn = 1.f / (float)n;
            #pragma unroll
            for (int l = 0; l < 8; ++l) {
                const f32x4 m0 = Mreg[l * 2], m1 = Mreg[l * 2 + 1];
                const float pl = P[l];
                #pragma unroll
                for (int c = 0; c < 4; ++c) {
                    tmp[c]     = fmaf(pl, m0[c], tmp[c]);
                    tmp[4 + c] = fmaf(pl, m1[c], tmp[4 + c]);
                }
            }
            #pragma unroll
            for (int c = 0; c < 8; ++c) { P[c] = tmp[c] * invn; res[c] += P[c]; }
        }
        const float av = aavg[((long)b * 512 + i0 + mi) * 512 + j];
        bf16x8 o;
        #pragma unroll
        for (int c = 0; c < 8; ++c) o[c] = (short)f2bf(res[c] * av);
        *(bf16x8*)(Gw + ((long)(b * 8 + r8) * 512 + (i0 + mi)) * 4096 + (long)j * 8) = o;
    }
}

// LayerNorm over last dim (2048) -> bf16 out. One block per row.
__global__ __launch_bounds__(256)
void lnbf_k(const float* __restrict__ h, const float* __restrict__ g,
            const float* __restrict__ b, unsigned short* __restrict__ out)
{
    const long row = blockIdx.x;
    const float* r = h + row * (long)DFF;
    const int tid = threadIdx.x;
    float vals[8];
    float s = 0.f, sq = 0.f;
    #pragma unroll
    for (int e = 0; e < 8; ++e) {
        const float v = r[tid + e * 256];
        vals[e] = v; s += v; sq += v * v;
    }
    __shared__ float rs[256], rq[256];
    rs[tid] = s; rq[tid] = sq; __syncthreads();
    for (int st = 128; st > 0; st >>= 1) {
        if (tid < st) { rs[tid] += rs[tid + st]; rq[tid] += rq[tid + st]; }
        __syncthreads();
    }
    const float mean = rs[0] * (1.f / DFF);
    const float var  = rq[0] * (1.f / DFF) - mean * mean;
    const float inv  = rsqrtf(var + 1e-5f);
    unsigned short* o = out + row * (long)DFF;
    #pragma unroll
    for (int e = 0; e < 8; ++e) {
        const int c = tid + e * 256;
        o[c] = f2bf((vals[e] - mean) * inv * g[c] + b[c]);
    }
}

// [R][C] fp32 -> [C][R] bf16 transpose
__global__ __launch_bounds__(256)
void tconv_k(const float* __restrict__ in, unsigned short* __restrict__ out,
             int R, int C)
{
    __shared__ float Ls[64][65];
    const int c0 = blockIdx.x * 64, r0 = blockIdx.y * 64;
    const int tid = threadIdx.x;
    const int tc = tid & 63, tr = tid >> 6;
    #pragma unroll
    for (int p = 0; p < 16; ++p)
        Ls[tr + p * 4][tc] = in[(long)(r0 + tr + p * 4) * C + c0 + tc];
    __syncthreads();
    #pragma unroll
    for (int p = 0; p < 16; ++p)
        out[(long)(c0 + tr + p * 4) * R + r0 + tc] = f2bf(Ls[tc][tr + p * 4]);
}

// four 512x512 fp32 -> bf16 transposes in one launch (z selects matrix);
// outputs contiguous at outbase + z*262144 (Wqt,Wkt,Wvt,Wot layout).
__global__ __launch_bounds__(256)
void tconv4_k(const float* __restrict__ W0, const float* __restrict__ W1,
              const float* __restrict__ W2, const float* __restrict__ W3,
              unsigned short* __restrict__ outbase)
{
    __shared__ float Ls[64][65];
    const int z = blockIdx.z;
    const float* in = (z == 0) ? W0 : (z == 1) ? W1 : (z == 2) ? W2 : W3;
    unsigned short* out = outbase + (long)z * 262144;
    const int c0 = blockIdx.x * 64, r0 = blockIdx.y * 64;
    const int tid = threadIdx.x;
    const int tc = tid & 63, tr = tid >> 6;
    #pragma unroll
    for (int p = 0; p < 16; ++p)
        Ls[tr + p * 4][tc] = in[(long)(r0 + tr + p * 4) * 512 + c0 + tc];
    __syncthreads();
    #pragma unroll
    for (int p = 0; p < 16; ++p)
        out[(long)(c0 + tr + p * 4) * 512 + r0 + tc] = f2bf(Ls[tc][tr + p * 4]);
}

// Wfp [64][512] and Wfo [512][64] transposes in one launch (z selects).
__global__ __launch_bounds__(256)
void tconvfp_k(const float* __restrict__ Wfp, const float* __restrict__ Wfo,
               unsigned short* __restrict__ ofp, unsigned short* __restrict__ ofo)
{
    __shared__ float Ls[64][65];
    const int z = blockIdx.z;
    const float* in = z ? Wfo : Wfp;
    unsigned short* out = z ? ofo : ofp;
    const int R = z ? 512 : 64, C = z ? 64 : 512;
    const int c0 = z ? 0 : blockIdx.x * 64;
    const int r0 = z ? blockIdx.x * 64 : 0;
    const int tid = threadIdx.x;
    const int tc = tid & 63, tr = tid >> 6;
    #pragma unroll
    for (int p = 0; p < 16; ++p)
        Ls[tr + p * 4][tc] = in[(long)(r0 + tr + p * 4) * C + c0 + tc];
    __syncthreads();
    #pragma unroll
    for (int p = 0; p < 16; ++p)
        out[(long)(c0 + tr + p * 4) * R + r0 + tc] = f2bf(Ls[tc][tr + p * 4]);
}

// Wc2 [2048][32768] fp32 -> Wc2p [32768][2048] bf16: out[kl*512+d][f] = in[f][d*64+kl]
__global__ __launch_bounds__(256)
void wc2p_k(const float* __restrict__ in, unsigned short* __restrict__ out)
{
    __shared__ float Ls[64][65];
    const int d0 = blockIdx.x;
    const long f0 = blockIdx.y * 64;
    const int tid = threadIdx.x;
    const int tc = tid & 63, tr = tid >> 6;
    #pragma unroll
    for (int p = 0; p < 16; ++p)
        Ls[tr + p * 4][tc] = in[(f0 + tr + p * 4) * 32768 + (long)d0 * 64 + tc];
    __syncthreads();
    #pragma unroll
    for (int p = 0; p < 16; ++p) {
        const int kl = tr + p * 4;
        out[((long)kl * 512 + d0) * 2048 + f0 + tc] = f2bf(Ls[tc][kl]);
    }
}

// x (524288) and u (65536) fp32->bf16 in one launch; blocks [0,2048) x, rest u.
__global__ __launch_bounds__(256)
void f2bfxu_k(const float* __restrict__ x, const float* __restrict__ u,
              unsigned short* __restrict__ xo, unsigned short* __restrict__ uo)
{
    const int bid = blockIdx.x;
    if (bid < 2048) {
        const int i = bid * 256 + threadIdx.x;
        xo[i] = f2bf(x[i]);
    } else {
        const int i = (bid - 2048) * 256 + threadIdx.x;
        uo[i] = f2bf(u[i]);
    }
}

extern "C" void kernel_launch(void* const* d_in, const int* in_sizes, int n_in,
                              void* d_out, int out_size, void* d_ws, size_t ws_size,
                              hipStream_t stream) {
    const float* x   = (const float*)d_in[0];
    const float* u   = (const float*)d_in[1];
    const float* Wq  = (const float*)d_in[2];  const float* bq  = (const float*)d_in[3];
    const float* Wk  = (const float*)d_in[4];  const float* bk  = (const float*)d_in[5];
    const float* Wv  = (const float*)d_in[6];  const float* bv  = (const float*)d_in[7];
    const float* Wo  = (const float*)d_in[8];  const float* bo  = (const float*)d_in[9];
    const float* Wfp = (const float*)d_in[10]; const float* bfp = (const float*)d_in[11];
    const float* Wfo = (const float*)d_in[12]; const float* bfo = (const float*)d_in[13];
    const float* Wc1 = (const float*)d_in[14]; const float* bc1 = (const float*)d_in[15];
    const float* gln = (const float*)d_in[16]; const float* bln = (const float*)d_in[17];
    const float* Wc2 = (const float*)d_in[18]; const float* bc2 = (const float*)d_in[19];

    float* ws = (float*)d_ws;
    // float-unit offsets; Gw aliases Wc2p (dead after fc2). Peak ~313 MB.
    unsigned short* Wc2p = (unsigned short*)(ws);                     // 33,554,432 fu
    unsigned short* Gw   = (unsigned short*)(ws);                     // alias
    unsigned short* At   = (unsigned short*)(ws + 33554432);          // 16,777,216 fu
    float*          h    = ws + 50331648;                             //  2,097,152 fu
    unsigned short* h_bf = (unsigned short*)(ws + 52428800);          //  1,048,576 fu
    unsigned short* x_bf = (unsigned short*)(ws + 53477376);          //    262,144 fu
    unsigned short* u_bf = (unsigned short*)(ws + 53739520);          //     32,768 fu
    unsigned short* Wc1t = (unsigned short*)(ws + 53772288);          //    524,288 fu
    unsigned short* Wqt  = (unsigned short*)(ws + 54296576);          //    131,072 fu
    unsigned short* Wkt  = (unsigned short*)(ws + 54427648);          // (contiguous
    unsigned short* Wvt  = (unsigned short*)(ws + 54558720);          //  after Wqt)
    unsigned short* Wot  = (unsigned short*)(ws + 54689792);
    unsigned short* Wfpt = (unsigned short*)(ws + 54820864);          //     16,384 fu
    unsigned short* Wfot = (unsigned short*)(ws + 54837248);          //     16,384 fu
    unsigned short* q_bf = (unsigned short*)(ws + 54919168);          //    262,144 fu
    unsigned short* k_bf = (unsigned short*)(ws + 55181312);
    unsigned short* vT   = (unsigned short*)(ws + 55443456);
    unsigned short* at_bf= (unsigned short*)(ws + 59899904);          //  2,097,152 fu
    float*          av   = ws + 61997056;                             //    524,288 fu
    unsigned short* ctx  = (unsigned short*)(ws + 62521344);          //    262,144 fu
    unsigned short* upT2 = (unsigned short*)(ws + 62783488);
    unsigned short* ut_bf= (unsigned short*)(ws + 63045632);
    // split-K fp32 partial buffers
    float*          qkvp = ws + 63307776;                             //  6,291,456 fu
    float*          wop  = ws + 69599232;                             //  2,097,152 fu
    float*          ctxp = ws + 71696384;
    float*          utp  = ws + 73793536;                             //  4,194,304 fu
    float*          up   = ws + 77987840;                             //    262,144 fu
    float* xout = (float*)d_out;
    float* uout = xout + 524288;

    const dim3 blk(256);

    // dynamic-LDS opt-ins (host-side, graph-capture safe)
    hipFuncSetAttribute(reinterpret_cast<const void*>(fc2_k),
                        hipFuncAttributeMaxDynamicSharedMemorySize, 163840);
    hipFuncSetAttribute(reinterpret_cast<const void*>(attn_k),
                        hipFuncAttributeMaxDynamicSharedMemorySize, 76800);

    // --- conversions ---
    tconv_k<<<dim3(32, 8), blk, 0, stream>>>(Wc1, Wc1t, 512, 2048);
    tconv4_k<<<dim3(8, 8, 4), blk, 0, stream>>>(Wq, Wk, Wv, Wo, Wqt);
    tconvfp_k<<<dim3(8, 1, 2), blk, 0, stream>>>(Wfp, Wfo, Wfpt, Wfot);
    wc2p_k<<<dim3(512, 32), blk, 0, stream>>>(Wc2, Wc2p);
    f2bfxu_k<<<dim3(2304), blk, 0, stream>>>(x, u, x_bf, u_bf);

    // --- attention: fused QKV projection (N=1536, split-K x4) + fused reduce ---
    mgemm_k<128,7,4><<<dim3(48, 8, 1), blk, 0, stream>>>(
        x_bf, Wqt, nullptr, nullptr, qkvp, nullptr, 512, 512, 512, 1536,
        1, 0,0,0,0, 0,1572864, 1.0f);
    redqkv_k<<<dim3(6, 1024), blk, 0, stream>>>(qkvp, bq, bk, bv, q_bf, k_bf, vT);
    // fused scores+softmax -> at_bf (sc fp32 eliminated)
    attn_k<<<dim3(8, 16), dim3(512), 76800, stream>>>(q_bf, k_bf, at_bf);
    aavg_k<<<dim3(512), blk, 0, stream>>>(at_bf, av);
    // ctx = attn @ v, batched (b,h), split-K x4
    mgemm_k<64,7,4><<<dim3(4, 4, 16), blk, 0, stream>>>(
        at_bf, vT, nullptr, nullptr, ctxp, nullptr, 512, 512, 512, 64,
        8, 2097152,262144, 262144,32768, 32768,524288, 1.0f);
    redzc_k<4><<<dim3(2048), blk, 0, stream>>>(ctxp, ctx);
    // x_out = x + ctx @ Wo + bo, split-K x4
    mgemm_k<128,7,4><<<dim3(16, 8, 1), blk, 0, stream>>>(
        ctx, Wot, nullptr, nullptr, wop, nullptr, 512, 512, 512, 512,
        1, 0,0,0,0, 0,524288, 1.0f);
    redwo_k<<<dim3(2048), blk, 0, stream>>>(wop, bo, x, xout);

    // --- connection network ---
    mgemm_k<128,1><<<dim3(16, 8, 1), blk, 0, stream>>>(
        x_bf, Wc1t, bc1, nullptr, h, nullptr, 512, 512, 512, 2048,
        1, 0,0,0,0,0,0, 1.0f);
    lnbf_k<<<dim3(1024), blk, 0, stream>>>(h, gln, bln, h_bf);
    // fc2: 256x256-tile 8-wave pipelined GEMM, B triple-buffered (2 tiles deep)
    fc2_k<<<dim3(512), dim3(512), 163840, stream>>>(h_bf, Wc2p, bc2, At);
    // liegamma computes xa in-kernel
    liegamma_k<<<dim3(4, 512, 2), blk, 0, stream>>>(x_bf, At, x, av, Gw);

    // --- fiber transport ---
    mgemm_k<128,6><<<dim3(4, 8, 1), blk, 0, stream>>>(
        u_bf, Wfpt, bfp, nullptr, nullptr, upT2, 64, 64, 64, 512,
        1, 0,0,0,0,0,0, 1.0f);
    // ut[b,i,k*64+c] = Gw[b,k] @ upT2[b]^T, batched (b,k), split-K x8
    mgemm_k<64,7,8><<<dim3(8, 4, 16), blk, 0, stream>>>(
        Gw, upT2, nullptr, nullptr, utp, nullptr, 4096, 4096, 4096, 64,
        8, 16777216,2097152, 262144,0, 32768,524288, 1.0f);
    redzc_k<8><<<dim3(2048), blk, 0, stream>>>(utp, ut_bf);
    // u_out = u + ut @ Wfo + bfo, split-K x4
    mgemm_k<64,7,4><<<dim3(4, 8, 1), blk, 0, stream>>>(
        ut_bf, Wfot, nullptr, nullptr, up, nullptr, 512, 512, 512, 64,
        1, 0,0,0,0, 0,65536, 1.0f);
    redu_k<<<dim3(256), blk, 0, stream>>>(up, bfo, u, uout);
}